// Round 7
// baseline (1122.387 us; speedup 1.0000x reference)
//
#include <hip/hip_runtime.h>
#include <math.h>

// ---------------- workspace layout (bytes) ----------------
constexpr size_t XW_OFF  = 0;                                   // 65536*384 f32 = 96 MB (dead after 2nd gru -> reused for norms)
constexpr size_t O1_OFF  = XW_OFF + 65536ull * 384 * 4;         // 32 MB
constexpr size_t O2_OFF  = O1_OFF + 512ull * 128 * 128 * 4;     // 32 MB
constexpr size_t Y0_OFF  = O2_OFF + 512ull * 128 * 128 * 4;     // 128 KB
constexpr size_t Y1_OFF  = Y0_OFF + 256ull * 128 * 4;           // 128 KB
constexpr size_t MMD_OFF = Y1_OFF + 256ull * 128 * 4;           // 1 KB
constexpr size_t WTS_OFF = MMD_OFF + 256 * 4;                   // 1 KB
constexpr size_t BW_OFF  = WTS_OFF + 256 * 4;                   // 1 KB
constexpr size_t NRM_OFF = XW_OFF;                              // norms[2][128][512] f32 = 512 KB (aliases xw)

// ---------------- K1/K3: C[M][N] = A[M][K] @ W[N][K]^T + bias[N] ----------------
__global__ __launch_bounds__(256) void gemm64(const float* __restrict__ A,
                                              const float* __restrict__ W,
                                              const float* __restrict__ bias,
                                              float* __restrict__ C,
                                              int M, int N, int K)
{
    __shared__ __align__(16) float As[64][36];
    __shared__ __align__(16) float Ws[64][36];
    const int tid = threadIdx.x;
    const int tx = tid & 15, ty = tid >> 4;
    const int m0 = blockIdx.x * 64, n0 = blockIdx.y * 64;

    float acc[4][4];
#pragma unroll
    for (int i = 0; i < 4; ++i)
#pragma unroll
        for (int j = 0; j < 4; ++j) acc[i][j] = 0.f;

#pragma unroll 1
    for (int kc = 0; kc < K; kc += 32) {
#pragma unroll
        for (int it = 0; it < 2; ++it) {
            int idx = tid + it * 256;          // 0..511
            int row = idx >> 3;
            int c4  = (idx & 7) * 4;
            float4 va = *(const float4*)(A + (size_t)(m0 + row) * K + kc + c4);
            *(float4*)&As[row][c4] = va;
            float4 vw = *(const float4*)(W + (size_t)(n0 + row) * K + kc + c4);
            *(float4*)&Ws[row][c4] = vw;
        }
        __syncthreads();
#pragma unroll 1
        for (int k0 = 0; k0 < 32; k0 += 4) {
            float4 a4[4], w4[4];
#pragma unroll
            for (int i = 0; i < 4; ++i) a4[i] = *(float4*)&As[ty + 16 * i][k0];
#pragma unroll
            for (int j = 0; j < 4; ++j) w4[j] = *(float4*)&Ws[tx + 16 * j][k0];
#pragma unroll
            for (int i = 0; i < 4; ++i)
#pragma unroll
                for (int j = 0; j < 4; ++j) {
                    acc[i][j] += a4[i].x * w4[j].x + a4[i].y * w4[j].y +
                                 a4[i].z * w4[j].z + a4[i].w * w4[j].w;
                }
        }
        __syncthreads();
    }
#pragma unroll
    for (int i = 0; i < 4; ++i)
#pragma unroll
        for (int j = 0; j < 4; ++j) {
            int r = m0 + ty + 16 * i, c = n0 + tx + 16 * j;
            C[(size_t)r * N + c] = acc[i][j] + bias[c];
        }
}

// ---------------- K2/K4: GRU scan ----------------
// R6 post-mortem: 128 weight floats/thread never stays register-resident
// (VGPR=92 despite pin) -> per-step L2 refetch ~186us. New structure:
// 768 threads, thread (og=t>>3, ks=t&7) owns rows 4og..4og+3 x k-slice
// [16ks,16ks+16) = 16 float4 = 64 floats (fits). 3-stage shfl_xor(1/2/4)
// reduce over ks; lanes ks<4 own output j=4og+(ks&3) (same j map as before).
// XOR bank swizzle: quad q reads h at 4*(q^(ks&3)) -> 2-way max (free).
__global__ __launch_bounds__(768, 3) void gru_scan(const float* __restrict__ xw,
                                                   const float* __restrict__ whh,
                                                   const float* __restrict__ bhh,
                                                   float* __restrict__ out)
{
    const int b0 = blockIdx.x * 2;
    const int t  = threadIdx.x;            // 0..767
    const int ks = t & 7;
    const int og = t >> 3;                 // 0..95
    const int e  = ks & 3;
    const int rown = ks & 3;               // row kept after reduce
    const int j  = 4 * og + rown;          // output index (authoritative for ks<4)

    const int o0 = 4 * (0 ^ e), o1 = 4 * (1 ^ e), o2 = 4 * (2 ^ e), o3 = 4 * (3 ^ e);

    const float* wb = whh + (size_t)(4 * og) * 128 + 16 * ks;
#define LDQ(r, q, oq) float4 w##r##_##q = *(const float4*)(wb + (r) * 128 + (oq));
    LDQ(0,0,o0) LDQ(0,1,o1) LDQ(0,2,o2) LDQ(0,3,o3)
    LDQ(1,0,o0) LDQ(1,1,o1) LDQ(1,2,o2) LDQ(1,3,o3)
    LDQ(2,0,o0) LDQ(2,1,o1) LDQ(2,2,o2) LDQ(2,3,o3)
    LDQ(3,0,o0) LDQ(3,1,o1) LDQ(3,2,o2) LDQ(3,3,o3)
#undef LDQ
#define PIN(v) asm volatile("" : "+v"(v.x), "+v"(v.y), "+v"(v.z), "+v"(v.w))
    PIN(w0_0); PIN(w0_1); PIN(w0_2); PIN(w0_3);
    PIN(w1_0); PIN(w1_1); PIN(w1_2); PIN(w1_3);
    PIN(w2_0); PIN(w2_1); PIN(w2_2); PIN(w2_3);
    PIN(w3_0); PIN(w3_1); PIN(w3_2); PIN(w3_3);
#undef PIN

    const float bj = bhh[j];

    __shared__ __align__(16) float h_s[2][128];
    __shared__ float rz_s[2][256];
    __shared__ float xn_s[2][128];
    __shared__ float hn_s[2][128];
    if (t < 256) h_s[t >> 7][t & 127] = 0.f;
    __syncthreads();

    const float* xwb0 = xw + (size_t)b0 * 128 * 384;
    const float* xwb1 = xwb0 + 128 * 384;

    float xv0 = 0.f, xv1 = 0.f;
    if (ks < 4) { xv0 = xwb0[j]; xv1 = xwb1[j]; }

#pragma unroll 1
    for (int st = 0; st < 128; ++st) {
        float nx0 = 0.f, nx1 = 0.f;
        if (st < 127 && ks < 4) {
            nx0 = xwb0[(st + 1) * 384 + j];
            nx1 = xwb1[(st + 1) * 384 + j];
        }

#define MQ(q, oq, hp) { float4 hv = *(const float4*)((hp) + (oq));                       \
        a0 += w0_##q.x * hv.x + w0_##q.y * hv.y + w0_##q.z * hv.z + w0_##q.w * hv.w;     \
        a1 += w1_##q.x * hv.x + w1_##q.y * hv.y + w1_##q.z * hv.z + w1_##q.w * hv.w;     \
        a2 += w2_##q.x * hv.x + w2_##q.y * hv.y + w2_##q.z * hv.z + w2_##q.w * hv.w;     \
        a3 += w3_##q.x * hv.x + w3_##q.y * hv.y + w3_##q.z * hv.z + w3_##q.w * hv.w; }

        // ---- batch row 0 ----
        const float* hp0 = &h_s[0][16 * ks];
        float a0 = 0.f, a1 = 0.f, a2 = 0.f, a3 = 0.f;
        MQ(0, o0, hp0) MQ(1, o1, hp0) MQ(2, o2, hp0) MQ(3, o3, hp0)
        a0 += __shfl_xor(a0, 1); a0 += __shfl_xor(a0, 2); a0 += __shfl_xor(a0, 4);
        a1 += __shfl_xor(a1, 1); a1 += __shfl_xor(a1, 2); a1 += __shfl_xor(a1, 4);
        a2 += __shfl_xor(a2, 1); a2 += __shfl_xor(a2, 2); a2 += __shfl_xor(a2, 4);
        a3 += __shfl_xor(a3, 1); a3 += __shfl_xor(a3, 2); a3 += __shfl_xor(a3, 4);
        float hw0 = ((rown == 0) ? a0 : (rown == 1) ? a1 : (rown == 2) ? a2 : a3) + bj;

        // ---- batch row 1 ----
        const float* hp1 = &h_s[1][16 * ks];
        a0 = 0.f; a1 = 0.f; a2 = 0.f; a3 = 0.f;
        MQ(0, o0, hp1) MQ(1, o1, hp1) MQ(2, o2, hp1) MQ(3, o3, hp1)
        a0 += __shfl_xor(a0, 1); a0 += __shfl_xor(a0, 2); a0 += __shfl_xor(a0, 4);
        a1 += __shfl_xor(a1, 1); a1 += __shfl_xor(a1, 2); a1 += __shfl_xor(a1, 4);
        a2 += __shfl_xor(a2, 1); a2 += __shfl_xor(a2, 2); a2 += __shfl_xor(a2, 4);
        a3 += __shfl_xor(a3, 1); a3 += __shfl_xor(a3, 2); a3 += __shfl_xor(a3, 4);
        float hw1 = ((rown == 0) ? a0 : (rown == 1) ? a1 : (rown == 2) ? a2 : a3) + bj;
#undef MQ

        if (ks < 4) {
            const int g = j >> 7, u = j & 127;
            if (g == 0)      { rz_s[0][u] = xv0 + hw0;        rz_s[1][u] = xv1 + hw1; }
            else if (g == 1) { rz_s[0][128 + u] = xv0 + hw0;  rz_s[1][128 + u] = xv1 + hw1; }
            else             { xn_s[0][u] = xv0; hn_s[0][u] = hw0;
                               xn_s[1][u] = xv1; hn_s[1][u] = hw1; }
        }
        __syncthreads();
        if (t < 256) {
            const int rr = t >> 7, uu = t & 127;
            float r = 1.f / (1.f + __expf(-rz_s[rr][uu]));
            float z = 1.f / (1.f + __expf(-rz_s[rr][128 + uu]));
            float xa = xn_s[rr][uu] + r * hn_s[rr][uu];
            float ex = __expf(-2.f * fabsf(xa));
            float th = (1.f - ex) / (1.f + ex);
            th = copysignf(th, xa);
            float hnew = (1.f - z) * th + z * h_s[rr][uu];
            h_s[rr][uu] = hnew;
            out[((size_t)(b0 + rr) * 128 + st) * 128 + uu] = hnew;
        }
        __syncthreads();
        xv0 = nx0; xv1 = nx1;
    }
}

// ---------------- K5: y[256][128] += xall @ gw^T (split-K, atomic) ----------------
__global__ __launch_bounds__(256) void gate_gemm(const float* __restrict__ o,
                                                 const float* __restrict__ gw,
                                                 float* __restrict__ y)
{
    __shared__ __align__(16) float As[64][36];
    __shared__ __align__(16) float Ws[64][36];
    const int tid = threadIdx.x;
    const int tx = tid & 15, ty = tid >> 4;
    const int m0 = blockIdx.x * 64, n0 = blockIdx.y * 64;
    const int k0beg = blockIdx.z * 1024;

    float acc[4][4];
#pragma unroll
    for (int i = 0; i < 4; ++i)
#pragma unroll
        for (int j = 0; j < 4; ++j) acc[i][j] = 0.f;

#pragma unroll 1
    for (int kc = k0beg; kc < k0beg + 1024; kc += 32) {
#pragma unroll
        for (int it = 0; it < 2; ++it) {
            int idx = tid + it * 256;
            int row = idx >> 3;
            int c4  = (idx & 7) * 4;
            int kap = kc + c4;
            int s = kap >> 8, half = (kap >> 7) & 1, h = kap & 127;
            float4 va = *(const float4*)(o + ((size_t)(m0 + row + 256 * half) * 128 + s) * 128 + h);
            *(float4*)&As[row][c4] = va;
            float4 vw = *(const float4*)(gw + (size_t)(n0 + row) * 32768 + kap);
            *(float4*)&Ws[row][c4] = vw;
        }
        __syncthreads();
#pragma unroll 1
        for (int k0 = 0; k0 < 32; k0 += 4) {
            float4 a4[4], w4[4];
#pragma unroll
            for (int i = 0; i < 4; ++i) a4[i] = *(float4*)&As[ty + 16 * i][k0];
#pragma unroll
            for (int j = 0; j < 4; ++j) w4[j] = *(float4*)&Ws[tx + 16 * j][k0];
#pragma unroll
            for (int i = 0; i < 4; ++i)
#pragma unroll
                for (int j = 0; j < 4; ++j) {
                    acc[i][j] += a4[i].x * w4[j].x + a4[i].y * w4[j].y +
                                 a4[i].z * w4[j].z + a4[i].w * w4[j].w;
                }
        }
        __syncthreads();
    }
#pragma unroll
    for (int i = 0; i < 4; ++i)
#pragma unroll
        for (int j = 0; j < 4; ++j) {
            int r = m0 + ty + 16 * i, c = n0 + tx + 16 * j;
            atomicAdd(&y[r * 128 + c], acc[i][j]);
        }
}

// ---------------- K6: BN + sigmoid-mean + softmax -> weights (128) ----------------
__global__ void gate_reduce(const float* __restrict__ y,
                            const float* __restrict__ gamma,
                            const float* __restrict__ beta,
                            float* __restrict__ wts_ws,
                            float* __restrict__ wts_out)
{
    const int o = threadIdx.x;   // 128 threads
    float sum = 0.f, sumsq = 0.f;
    for (int b = 0; b < 256; ++b) {
        float v = y[b * 128 + o];
        sum += v; sumsq += v * v;
    }
    float m = sum * (1.f / 256.f);
    float var = sumsq * (1.f / 256.f) - m * m;
    float inv = rsqrtf(var + 1e-5f);
    float g = gamma[o], be = beta[o];
    float sw = 0.f;
    for (int b = 0; b < 256; ++b) {
        float v = y[b * 128 + o];
        float t = g * (v - m) * inv + be;
        sw += 1.f / (1.f + __expf(-t));
    }
    float wo = sw * (1.f / 256.f);

    __shared__ float red[128];
    red[o] = wo;
    __syncthreads();
    for (int st = 64; st > 0; st >>= 1) {
        if (o < st) red[o] = fmaxf(red[o], red[o + st]);
        __syncthreads();
    }
    float mx = red[0];
    __syncthreads();
    float e = __expf(wo - mx);
    red[o] = e;
    __syncthreads();
    for (int st = 64; st > 0; st >>= 1) {
        if (o < st) red[o] += red[o + st];
        __syncthreads();
    }
    float r = e / red[0];
    wts_ws[o] = r;
    wts_out[o] = r;
}

// ---------------- K7: fc_out = o2[:, -1, :] @ fc_w^T + fc_b ----------------
__global__ void fc_kern(const float* __restrict__ o2,
                        const float* __restrict__ fw,
                        const float* __restrict__ fb,
                        float* __restrict__ out)
{
    int gid = blockIdx.x * blockDim.x + threadIdx.x;
    if (gid >= 3072) return;
    int b = gid / 6, oo = gid - b * 6;
    const float* xr = o2 + ((size_t)b * 128 + 127) * 128;
    const float* wr = fw + oo * 128;
    float acc = fb[oo];
#pragma unroll 16
    for (int k = 0; k < 128; ++k) acc += xr[k] * wr[k];
    out[gid] = acc;
}

// ---------------- K8a: per-row norms ----------------
__global__ __launch_bounds__(512) void row_norms(const float* __restrict__ o1,
                                                 const float* __restrict__ o2,
                                                 float* __restrict__ norms)
{
    const int s = blockIdx.x;          // 128
    const int l = blockIdx.y;          // 2
    const float* o = l ? o2 : o1;
    const int i = threadIdx.x;         // 512 rows
    const float* r = o + ((size_t)i * 128 + s) * 128;
    float acc = 0.f;
#pragma unroll
    for (int k = 0; k < 128; k += 4) {
        float4 v = *(const float4*)(r + k);
        acc += v.x * v.x + v.y * v.y + v.z * v.z + v.w * v.w;
    }
    norms[((size_t)l * 128 + s) * 512 + i] = acc;
}

// ---------------- K8b: per-pair bandwidth ----------------
__global__ void pair_stats(const float* __restrict__ o1,
                           const float* __restrict__ o2,
                           float* __restrict__ bw)
{
    const int p = blockIdx.x;          // 256 pairs
    const int l = p >> 7, s = p & 127;
    const float* o = l ? o2 : o1;
    const int tid = threadIdx.x;       // 256
    const int h = tid & 127, half = tid >> 7;

    float acc_u = 0.f, acc_sq = 0.f;
    for (int r = 0; r < 256; ++r) {
        int i = half * 256 + r;
        float v = o[((size_t)i * 128 + s) * 128 + h];
        acc_u += v; acc_sq += v * v;
    }
    __shared__ float u2[256];
    __shared__ float red[256];
    u2[tid] = acc_u;
    red[tid] = acc_sq;
    __syncthreads();
    for (int st = 128; st > 0; st >>= 1) {
        if (tid < st) red[tid] += red[tid + st];
        __syncthreads();
    }
    float S1 = red[0];
    __syncthreads();
    float uu = 0.f;
    if (tid < 128) { float t = u2[tid] + u2[tid + 128]; uu = t * t; }
    red[tid] = uu;
    __syncthreads();
    for (int st = 128; st > 0; st >>= 1) {
        if (tid < st) red[tid] += red[tid + st];
        __syncthreads();
    }
    if (tid == 0) {
        float S2 = red[0];
        float d2s = 1024.f * S1 - 2.f * S2;
        bw[p] = d2s / (512.f * 512.f - 512.f) * 0.25f;
    }
}

// ---------------- K9: MMD Gram + 5-kernel sum, symmetric tiles ----------------
__global__ __launch_bounds__(256) void mmd_kern(const float* __restrict__ o1,
                                                const float* __restrict__ o2,
                                                const float* __restrict__ norms,
                                                const float* __restrict__ bw,
                                                float* __restrict__ mmdv)
{
    const int lin = blockIdx.x;               // 0..2559
    const int v   = (lin & 7) * 320 + (lin >> 3);
    const int p   = v / 10;                   // pair
    const int tp  = v - p * 10;               // tile-pair
    int ti, tj;
    if (tp < 4)      { ti = 0; tj = tp; }
    else if (tp < 7) { ti = 1; tj = tp - 3; }
    else if (tp < 9) { ti = 2; tj = tp - 5; }
    else             { ti = 3; tj = 3; }
    const int l = p >> 7, s = p & 127;
    const float* o = l ? o2 : o1;
    const float sgn  = ((ti < 2) == (tj < 2)) ? 1.f : -1.f;
    const float coef = sgn * ((ti == tj) ? 1.f : 2.f);

    __shared__ __align__(16) float As[128][36];
    __shared__ __align__(16) float Bs[128][36];
    __shared__ float rbuf[4];

    const int tid = threadIdx.x;
    const int tx = tid & 15, ty = tid >> 4;

    float acc[8][8];
#pragma unroll
    for (int i = 0; i < 8; ++i)
#pragma unroll
        for (int j = 0; j < 8; ++j) acc[i][j] = 0.f;

#pragma unroll 1
    for (int kc = 0; kc < 128; kc += 32) {
#pragma unroll
        for (int it = 0; it < 4; ++it) {
            int idx = tid + it * 256;           // 0..1023
            int row = idx >> 3;
            int c4  = (idx & 7) * 4;
            float4 va = *(const float4*)(o + ((size_t)(ti * 128 + row) * 128 + s) * 128 + kc + c4);
            *(float4*)&As[row][c4] = va;
            float4 vb = *(const float4*)(o + ((size_t)(tj * 128 + row) * 128 + s) * 128 + kc + c4);
            *(float4*)&Bs[row][c4] = vb;
        }
        __syncthreads();
#pragma unroll 1
        for (int k0 = 0; k0 < 32; k0 += 4) {
            float4 b4[8];
#pragma unroll
            for (int j = 0; j < 8; ++j) b4[j] = *(float4*)&Bs[tx + 16 * j][k0];
#pragma unroll
            for (int i = 0; i < 8; ++i) {
                float4 a4 = *(float4*)&As[ty + 16 * i][k0];
#pragma unroll
                for (int j = 0; j < 8; ++j) {
                    acc[i][j] += a4.x * b4[j].x + a4.y * b4[j].y +
                                 a4.z * b4[j].z + a4.w * b4[j].w;
                }
            }
        }
        __syncthreads();
    }

    const float* np_ = norms + (size_t)p * 512;
    float na[8], nb[8];
#pragma unroll
    for (int i = 0; i < 8; ++i) na[i] = np_[ti * 128 + ty + 16 * i];
#pragma unroll
    for (int j = 0; j < 8; ++j) nb[j] = np_[tj * 128 + tx + 16 * j];

    const float bwv = bw[p];
    float c0 = -1.f / bwv;
    float c1 = c0 * 0.5f, c2 = c1 * 0.5f, c3 = c2 * 0.5f, c4v = c3 * 0.5f;
    float tot = 0.f;
#pragma unroll
    for (int i = 0; i < 8; ++i) {
#pragma unroll
        for (int j = 0; j < 8; ++j) {
            float d2 = na[i] + nb[j] - 2.f * acc[i][j];
            float kv = __expf(c0 * d2) + __expf(c1 * d2) + __expf(c2 * d2) +
                       __expf(c3 * d2) + __expf(c4v * d2);
            tot += kv;
        }
    }
    tot *= coef;

    for (int off = 32; off > 0; off >>= 1) tot += __shfl_down(tot, off);
    if ((tid & 63) == 0) rbuf[tid >> 6] = tot;
    __syncthreads();
    if (tid == 0) atomicAdd(&mmdv[p], rbuf[0] + rbuf[1] + rbuf[2] + rbuf[3]);
}

// ---------------- K10: loss = sum(wts * mmd) / 65536 ----------------
__global__ void final_loss(const float* __restrict__ wts,
                           const float* __restrict__ mmdv,
                           float* __restrict__ out)
{
    const int t = threadIdx.x;  // 256
    float v = wts[t] * mmdv[t];
    __shared__ float red[256];
    red[t] = v;
    __syncthreads();
    for (int st = 128; st > 0; st >>= 1) {
        if (t < st) red[t] += red[t + st];
        __syncthreads();
    }
    if (t == 0) out[0] = red[0] * (1.f / 65536.f);
}

// ---------------- launch ----------------
extern "C" void kernel_launch(void* const* d_in, const int* in_sizes, int n_in,
                              void* d_out, int out_size, void* d_ws, size_t ws_size,
                              hipStream_t stream)
{
    (void)in_sizes; (void)n_in; (void)out_size; (void)ws_size;
    const float* x    = (const float*)d_in[0];
    const float* wih0 = (const float*)d_in[1];
    const float* whh0 = (const float*)d_in[2];
    const float* bih0 = (const float*)d_in[3];
    const float* bhh0 = (const float*)d_in[4];
    const float* wih1 = (const float*)d_in[5];
    const float* whh1 = (const float*)d_in[6];
    const float* bih1 = (const float*)d_in[7];
    const float* bhh1 = (const float*)d_in[8];
    const float* gw0  = (const float*)d_in[9];
    const float* bg0  = (const float*)d_in[11];
    const float* bb0  = (const float*)d_in[12];
    const float* gw1  = (const float*)d_in[13];
    const float* bg1  = (const float*)d_in[15];
    const float* bb1  = (const float*)d_in[16];
    const float* fcw  = (const float*)d_in[17];
    const float* fcb  = (const float*)d_in[18];

    float* out = (float*)d_out;
    char*  ws  = (char*)d_ws;
    float* xw   = (float*)(ws + XW_OFF);
    float* o1   = (float*)(ws + O1_OFF);
    float* o2   = (float*)(ws + O2_OFF);
    float* y0   = (float*)(ws + Y0_OFF);
    float* y1   = (float*)(ws + Y1_OFF);
    float* mmdv = (float*)(ws + MMD_OFF);
    float* wts  = (float*)(ws + WTS_OFF);
    float* bwv  = (float*)(ws + BW_OFF);
    float* nrm  = (float*)(ws + NRM_OFF);   // aliases xw; valid after 2nd gru_scan

    hipMemsetAsync(y0, 0, (256 * 128 * 2 + 256) * sizeof(float), stream);

    gemm64<<<dim3(1024, 6), 256, 0, stream>>>(x, wih0, bih0, xw, 65536, 384, 128);
    gru_scan<<<256, 768, 0, stream>>>(xw, whh0, bhh0, o1);
    gemm64<<<dim3(1024, 6), 256, 0, stream>>>(o1, wih1, bih1, xw, 65536, 384, 128);
    gru_scan<<<256, 768, 0, stream>>>(xw, whh1, bhh1, o2);

    gate_gemm<<<dim3(4, 2, 32), 256, 0, stream>>>(o1, gw0, y0);
    gate_gemm<<<dim3(4, 2, 32), 256, 0, stream>>>(o2, gw1, y1);
    gate_reduce<<<1, 128, 0, stream>>>(y0, bg0, bb0, wts, out + 3073);
    gate_reduce<<<1, 128, 0, stream>>>(y1, bg1, bb1, wts + 128, out + 3073 + 128);

    fc_kern<<<12, 256, 0, stream>>>(o2, fcw, fcb, out);

    row_norms<<<dim3(128, 2), 512, 0, stream>>>(o1, o2, nrm);   // xw dead from here
    pair_stats<<<256, 256, 0, stream>>>(o1, o2, bwv);
    mmd_kern<<<2560, 256, 0, stream>>>(o1, o2, nrm, bwv, mmdv);
    final_loss<<<1, 256, 0, stream>>>(wts, mmdv, out + 3072);
}

// Round 8
// 1015.009 us; speedup vs baseline: 1.1058x; 1.1058x over previous
//
#include <hip/hip_runtime.h>
#include <math.h>

// ---------------- workspace layout (bytes) ----------------
constexpr size_t XW_OFF  = 0;                                   // 65536*384 f32 = 96 MB (dead after 2nd gru -> reused for norms)
constexpr size_t O1_OFF  = XW_OFF + 65536ull * 384 * 4;         // 32 MB
constexpr size_t O2_OFF  = O1_OFF + 512ull * 128 * 128 * 4;     // 32 MB
constexpr size_t Y0_OFF  = O2_OFF + 512ull * 128 * 128 * 4;     // 128 KB
constexpr size_t Y1_OFF  = Y0_OFF + 256ull * 128 * 4;           // 128 KB
constexpr size_t MMD_OFF = Y1_OFF + 256ull * 128 * 4;           // 1 KB
constexpr size_t WTS_OFF = MMD_OFF + 256 * 4;                   // 1 KB
constexpr size_t BW_OFF  = WTS_OFF + 256 * 4;                   // 1 KB
constexpr size_t NRM_OFF = XW_OFF;                              // norms[2][128][512] f32 = 512 KB (aliases xw)

// ---------------- K1/K3: C[M][N] = A[M][K] @ W[N][K]^T + bias[N] ----------------
__global__ __launch_bounds__(256) void gemm64(const float* __restrict__ A,
                                              const float* __restrict__ W,
                                              const float* __restrict__ bias,
                                              float* __restrict__ C,
                                              int M, int N, int K)
{
    __shared__ __align__(16) float As[64][36];
    __shared__ __align__(16) float Ws[64][36];
    const int tid = threadIdx.x;
    const int tx = tid & 15, ty = tid >> 4;
    const int m0 = blockIdx.x * 64, n0 = blockIdx.y * 64;

    float acc[4][4];
#pragma unroll
    for (int i = 0; i < 4; ++i)
#pragma unroll
        for (int j = 0; j < 4; ++j) acc[i][j] = 0.f;

#pragma unroll 1
    for (int kc = 0; kc < K; kc += 32) {
#pragma unroll
        for (int it = 0; it < 2; ++it) {
            int idx = tid + it * 256;          // 0..511
            int row = idx >> 3;
            int c4  = (idx & 7) * 4;
            float4 va = *(const float4*)(A + (size_t)(m0 + row) * K + kc + c4);
            *(float4*)&As[row][c4] = va;
            float4 vw = *(const float4*)(W + (size_t)(n0 + row) * K + kc + c4);
            *(float4*)&Ws[row][c4] = vw;
        }
        __syncthreads();
#pragma unroll 1
        for (int k0 = 0; k0 < 32; k0 += 4) {
            float4 a4[4], w4[4];
#pragma unroll
            for (int i = 0; i < 4; ++i) a4[i] = *(float4*)&As[ty + 16 * i][k0];
#pragma unroll
            for (int j = 0; j < 4; ++j) w4[j] = *(float4*)&Ws[tx + 16 * j][k0];
#pragma unroll
            for (int i = 0; i < 4; ++i)
#pragma unroll
                for (int j = 0; j < 4; ++j) {
                    acc[i][j] += a4[i].x * w4[j].x + a4[i].y * w4[j].y +
                                 a4[i].z * w4[j].z + a4[i].w * w4[j].w;
                }
        }
        __syncthreads();
    }
#pragma unroll
    for (int i = 0; i < 4; ++i)
#pragma unroll
        for (int j = 0; j < 4; ++j) {
            int r = m0 + ty + 16 * i, c = n0 + tx + 16 * j;
            C[(size_t)r * N + c] = acc[i][j] + bias[c];
        }
}

// ---------------- K2/K4: GRU scan ----------------
// R7 post-mortem: no scratch traffic -> weights ARE on-chip (unified reg file);
// the bottleneck is the LDS pipe: __shfl_xor lowers to ds_swizzle (24/thread/step
// = 1730 cyc/step) on top of 96 wave b128 h-reads (1150 cyc). Fix: intra-quad
// reduction stages via DPP quad_perm (VALU pipe, 0xB1 = xor1, 0x4E = xor2),
// select own acc BEFORE the xor4 stage -> shuffles/thread/step: 24 -> 2.
#define DPPADD(a, ctrl) { int yi_ = __builtin_amdgcn_mov_dpp(__float_as_int(a), ctrl, 0xF, 0xF, true); \
                          a += __int_as_float(yi_); }

__global__ __launch_bounds__(768, 3) void gru_scan(const float* __restrict__ xw,
                                                   const float* __restrict__ whh,
                                                   const float* __restrict__ bhh,
                                                   float* __restrict__ out)
{
    const int b0 = blockIdx.x * 2;
    const int t  = threadIdx.x;            // 0..767
    const int ks = t & 7;
    const int og = t >> 3;                 // 0..95
    const int e  = ks & 3;
    const int rown = ks & 3;               // row kept after reduce
    const int j  = 4 * og + rown;          // output index (authoritative for ks<4)

    const int o0 = 4 * (0 ^ e), o1 = 4 * (1 ^ e), o2 = 4 * (2 ^ e), o3 = 4 * (3 ^ e);

    const float* wb = whh + (size_t)(4 * og) * 128 + 16 * ks;
#define LDQ(r, q, oq) float4 w##r##_##q = *(const float4*)(wb + (r) * 128 + (oq));
    LDQ(0,0,o0) LDQ(0,1,o1) LDQ(0,2,o2) LDQ(0,3,o3)
    LDQ(1,0,o0) LDQ(1,1,o1) LDQ(1,2,o2) LDQ(1,3,o3)
    LDQ(2,0,o0) LDQ(2,1,o1) LDQ(2,2,o2) LDQ(2,3,o3)
    LDQ(3,0,o0) LDQ(3,1,o1) LDQ(3,2,o2) LDQ(3,3,o3)
#undef LDQ
#define PIN(v) asm volatile("" : "+v"(v.x), "+v"(v.y), "+v"(v.z), "+v"(v.w))
    PIN(w0_0); PIN(w0_1); PIN(w0_2); PIN(w0_3);
    PIN(w1_0); PIN(w1_1); PIN(w1_2); PIN(w1_3);
    PIN(w2_0); PIN(w2_1); PIN(w2_2); PIN(w2_3);
    PIN(w3_0); PIN(w3_1); PIN(w3_2); PIN(w3_3);
#undef PIN

    const float bj = bhh[j];

    __shared__ __align__(16) float h_s[2][128];
    __shared__ float rz_s[2][256];
    __shared__ float xn_s[2][128];
    __shared__ float hn_s[2][128];
    if (t < 256) h_s[t >> 7][t & 127] = 0.f;
    __syncthreads();

    const float* xwb0 = xw + (size_t)b0 * 128 * 384;
    const float* xwb1 = xwb0 + 128 * 384;

    float xv0 = 0.f, xv1 = 0.f;
    if (ks < 4) { xv0 = xwb0[j]; xv1 = xwb1[j]; }

#pragma unroll 1
    for (int st = 0; st < 128; ++st) {
        float nx0 = 0.f, nx1 = 0.f;
        if (st < 127 && ks < 4) {
            nx0 = xwb0[(st + 1) * 384 + j];
            nx1 = xwb1[(st + 1) * 384 + j];
        }

#define MQ(q, oq, hp) { float4 hv = *(const float4*)((hp) + (oq));                       \
        a0 += w0_##q.x * hv.x + w0_##q.y * hv.y + w0_##q.z * hv.z + w0_##q.w * hv.w;     \
        a1 += w1_##q.x * hv.x + w1_##q.y * hv.y + w1_##q.z * hv.z + w1_##q.w * hv.w;     \
        a2 += w2_##q.x * hv.x + w2_##q.y * hv.y + w2_##q.z * hv.z + w2_##q.w * hv.w;     \
        a3 += w3_##q.x * hv.x + w3_##q.y * hv.y + w3_##q.z * hv.z + w3_##q.w * hv.w; }

        // ---- batch row 0 ----
        const float* hp0 = &h_s[0][16 * ks];
        float a0 = 0.f, a1 = 0.f, a2 = 0.f, a3 = 0.f;
        MQ(0, o0, hp0) MQ(1, o1, hp0) MQ(2, o2, hp0) MQ(3, o3, hp0)
        DPPADD(a0, 0xB1) DPPADD(a0, 0x4E)
        DPPADD(a1, 0xB1) DPPADD(a1, 0x4E)
        DPPADD(a2, 0xB1) DPPADD(a2, 0x4E)
        DPPADD(a3, 0xB1) DPPADD(a3, 0x4E)
        float hw0 = ((rown == 0) ? a0 : (rown == 1) ? a1 : (rown == 2) ? a2 : a3);
        hw0 += __shfl_xor(hw0, 4);
        hw0 += bj;

        // ---- batch row 1 ----
        const float* hp1 = &h_s[1][16 * ks];
        a0 = 0.f; a1 = 0.f; a2 = 0.f; a3 = 0.f;
        MQ(0, o0, hp1) MQ(1, o1, hp1) MQ(2, o2, hp1) MQ(3, o3, hp1)
        DPPADD(a0, 0xB1) DPPADD(a0, 0x4E)
        DPPADD(a1, 0xB1) DPPADD(a1, 0x4E)
        DPPADD(a2, 0xB1) DPPADD(a2, 0x4E)
        DPPADD(a3, 0xB1) DPPADD(a3, 0x4E)
        float hw1 = ((rown == 0) ? a0 : (rown == 1) ? a1 : (rown == 2) ? a2 : a3);
        hw1 += __shfl_xor(hw1, 4);
        hw1 += bj;
#undef MQ

        if (ks < 4) {
            const int g = j >> 7, u = j & 127;
            if (g == 0)      { rz_s[0][u] = xv0 + hw0;        rz_s[1][u] = xv1 + hw1; }
            else if (g == 1) { rz_s[0][128 + u] = xv0 + hw0;  rz_s[1][128 + u] = xv1 + hw1; }
            else             { xn_s[0][u] = xv0; hn_s[0][u] = hw0;
                               xn_s[1][u] = xv1; hn_s[1][u] = hw1; }
        }
        __syncthreads();
        if (t < 256) {
            const int rr = t >> 7, uu = t & 127;
            float r = 1.f / (1.f + __expf(-rz_s[rr][uu]));
            float z = 1.f / (1.f + __expf(-rz_s[rr][128 + uu]));
            float xa = xn_s[rr][uu] + r * hn_s[rr][uu];
            float ex = __expf(-2.f * fabsf(xa));
            float th = (1.f - ex) / (1.f + ex);
            th = copysignf(th, xa);
            float hnew = (1.f - z) * th + z * h_s[rr][uu];
            h_s[rr][uu] = hnew;
            out[((size_t)(b0 + rr) * 128 + st) * 128 + uu] = hnew;
        }
        __syncthreads();
        xv0 = nx0; xv1 = nx1;
    }
}

// ---------------- K5: y[256][128] += xall @ gw^T (split-K, atomic) ----------------
__global__ __launch_bounds__(256) void gate_gemm(const float* __restrict__ o,
                                                 const float* __restrict__ gw,
                                                 float* __restrict__ y)
{
    __shared__ __align__(16) float As[64][36];
    __shared__ __align__(16) float Ws[64][36];
    const int tid = threadIdx.x;
    const int tx = tid & 15, ty = tid >> 4;
    const int m0 = blockIdx.x * 64, n0 = blockIdx.y * 64;
    const int k0beg = blockIdx.z * 1024;

    float acc[4][4];
#pragma unroll
    for (int i = 0; i < 4; ++i)
#pragma unroll
        for (int j = 0; j < 4; ++j) acc[i][j] = 0.f;

#pragma unroll 1
    for (int kc = k0beg; kc < k0beg + 1024; kc += 32) {
#pragma unroll
        for (int it = 0; it < 2; ++it) {
            int idx = tid + it * 256;
            int row = idx >> 3;
            int c4  = (idx & 7) * 4;
            int kap = kc + c4;
            int s = kap >> 8, half = (kap >> 7) & 1, h = kap & 127;
            float4 va = *(const float4*)(o + ((size_t)(m0 + row + 256 * half) * 128 + s) * 128 + h);
            *(float4*)&As[row][c4] = va;
            float4 vw = *(const float4*)(gw + (size_t)(n0 + row) * 32768 + kap);
            *(float4*)&Ws[row][c4] = vw;
        }
        __syncthreads();
#pragma unroll 1
        for (int k0 = 0; k0 < 32; k0 += 4) {
            float4 a4[4], w4[4];
#pragma unroll
            for (int i = 0; i < 4; ++i) a4[i] = *(float4*)&As[ty + 16 * i][k0];
#pragma unroll
            for (int j = 0; j < 4; ++j) w4[j] = *(float4*)&Ws[tx + 16 * j][k0];
#pragma unroll
            for (int i = 0; i < 4; ++i)
#pragma unroll
                for (int j = 0; j < 4; ++j) {
                    acc[i][j] += a4[i].x * w4[j].x + a4[i].y * w4[j].y +
                                 a4[i].z * w4[j].z + a4[i].w * w4[j].w;
                }
        }
        __syncthreads();
    }
#pragma unroll
    for (int i = 0; i < 4; ++i)
#pragma unroll
        for (int j = 0; j < 4; ++j) {
            int r = m0 + ty + 16 * i, c = n0 + tx + 16 * j;
            atomicAdd(&y[r * 128 + c], acc[i][j]);
        }
}

// ---------------- K6: BN + sigmoid-mean + softmax -> weights (128) ----------------
__global__ void gate_reduce(const float* __restrict__ y,
                            const float* __restrict__ gamma,
                            const float* __restrict__ beta,
                            float* __restrict__ wts_ws,
                            float* __restrict__ wts_out)
{
    const int o = threadIdx.x;   // 128 threads
    float sum = 0.f, sumsq = 0.f;
    for (int b = 0; b < 256; ++b) {
        float v = y[b * 128 + o];
        sum += v; sumsq += v * v;
    }
    float m = sum * (1.f / 256.f);
    float var = sumsq * (1.f / 256.f) - m * m;
    float inv = rsqrtf(var + 1e-5f);
    float g = gamma[o], be = beta[o];
    float sw = 0.f;
    for (int b = 0; b < 256; ++b) {
        float v = y[b * 128 + o];
        float t = g * (v - m) * inv + be;
        sw += 1.f / (1.f + __expf(-t));
    }
    float wo = sw * (1.f / 256.f);

    __shared__ float red[128];
    red[o] = wo;
    __syncthreads();
    for (int st = 64; st > 0; st >>= 1) {
        if (o < st) red[o] = fmaxf(red[o], red[o + st]);
        __syncthreads();
    }
    float mx = red[0];
    __syncthreads();
    float e = __expf(wo - mx);
    red[o] = e;
    __syncthreads();
    for (int st = 64; st > 0; st >>= 1) {
        if (o < st) red[o] += red[o + st];
        __syncthreads();
    }
    float r = e / red[0];
    wts_ws[o] = r;
    wts_out[o] = r;
}

// ---------------- K7: fc_out = o2[:, -1, :] @ fc_w^T + fc_b ----------------
__global__ void fc_kern(const float* __restrict__ o2,
                        const float* __restrict__ fw,
                        const float* __restrict__ fb,
                        float* __restrict__ out)
{
    int gid = blockIdx.x * blockDim.x + threadIdx.x;
    if (gid >= 3072) return;
    int b = gid / 6, oo = gid - b * 6;
    const float* xr = o2 + ((size_t)b * 128 + 127) * 128;
    const float* wr = fw + oo * 128;
    float acc = fb[oo];
#pragma unroll 16
    for (int k = 0; k < 128; ++k) acc += xr[k] * wr[k];
    out[gid] = acc;
}

// ---------------- K8a: per-row norms ----------------
__global__ __launch_bounds__(512) void row_norms(const float* __restrict__ o1,
                                                 const float* __restrict__ o2,
                                                 float* __restrict__ norms)
{
    const int s = blockIdx.x;          // 128
    const int l = blockIdx.y;          // 2
    const float* o = l ? o2 : o1;
    const int i = threadIdx.x;         // 512 rows
    const float* r = o + ((size_t)i * 128 + s) * 128;
    float acc = 0.f;
#pragma unroll
    for (int k = 0; k < 128; k += 4) {
        float4 v = *(const float4*)(r + k);
        acc += v.x * v.x + v.y * v.y + v.z * v.z + v.w * v.w;
    }
    norms[((size_t)l * 128 + s) * 512 + i] = acc;
}

// ---------------- K8b: per-pair bandwidth ----------------
__global__ void pair_stats(const float* __restrict__ o1,
                           const float* __restrict__ o2,
                           float* __restrict__ bw)
{
    const int p = blockIdx.x;          // 256 pairs
    const int l = p >> 7, s = p & 127;
    const float* o = l ? o2 : o1;
    const int tid = threadIdx.x;       // 256
    const int h = tid & 127, half = tid >> 7;

    float acc_u = 0.f, acc_sq = 0.f;
    for (int r = 0; r < 256; ++r) {
        int i = half * 256 + r;
        float v = o[((size_t)i * 128 + s) * 128 + h];
        acc_u += v; acc_sq += v * v;
    }
    __shared__ float u2[256];
    __shared__ float red[256];
    u2[tid] = acc_u;
    red[tid] = acc_sq;
    __syncthreads();
    for (int st = 128; st > 0; st >>= 1) {
        if (tid < st) red[tid] += red[tid + st];
        __syncthreads();
    }
    float S1 = red[0];
    __syncthreads();
    float uu = 0.f;
    if (tid < 128) { float t = u2[tid] + u2[tid + 128]; uu = t * t; }
    red[tid] = uu;
    __syncthreads();
    for (int st = 128; st > 0; st >>= 1) {
        if (tid < st) red[tid] += red[tid + st];
        __syncthreads();
    }
    if (tid == 0) {
        float S2 = red[0];
        float d2s = 1024.f * S1 - 2.f * S2;
        bw[p] = d2s / (512.f * 512.f - 512.f) * 0.25f;
    }
}

// ---------------- K9: MMD Gram + 5-kernel sum, symmetric tiles ----------------
__global__ __launch_bounds__(256) void mmd_kern(const float* __restrict__ o1,
                                                const float* __restrict__ o2,
                                                const float* __restrict__ norms,
                                                const float* __restrict__ bw,
                                                float* __restrict__ mmdv)
{
    const int lin = blockIdx.x;               // 0..2559
    const int v   = (lin & 7) * 320 + (lin >> 3);
    const int p   = v / 10;                   // pair
    const int tp  = v - p * 10;               // tile-pair
    int ti, tj;
    if (tp < 4)      { ti = 0; tj = tp; }
    else if (tp < 7) { ti = 1; tj = tp - 3; }
    else if (tp < 9) { ti = 2; tj = tp - 5; }
    else             { ti = 3; tj = 3; }
    const int l = p >> 7, s = p & 127;
    const float* o = l ? o2 : o1;
    const float sgn  = ((ti < 2) == (tj < 2)) ? 1.f : -1.f;
    const float coef = sgn * ((ti == tj) ? 1.f : 2.f);

    __shared__ __align__(16) float As[128][36];
    __shared__ __align__(16) float Bs[128][36];
    __shared__ float rbuf[4];

    const int tid = threadIdx.x;
    const int tx = tid & 15, ty = tid >> 4;

    float acc[8][8];
#pragma unroll
    for (int i = 0; i < 8; ++i)
#pragma unroll
        for (int j = 0; j < 8; ++j) acc[i][j] = 0.f;

#pragma unroll 1
    for (int kc = 0; kc < 128; kc += 32) {
#pragma unroll
        for (int it = 0; it < 4; ++it) {
            int idx = tid + it * 256;           // 0..1023
            int row = idx >> 3;
            int c4  = (idx & 7) * 4;
            float4 va = *(const float4*)(o + ((size_t)(ti * 128 + row) * 128 + s) * 128 + kc + c4);
            *(float4*)&As[row][c4] = va;
            float4 vb = *(const float4*)(o + ((size_t)(tj * 128 + row) * 128 + s) * 128 + kc + c4);
            *(float4*)&Bs[row][c4] = vb;
        }
        __syncthreads();
#pragma unroll 1
        for (int k0 = 0; k0 < 32; k0 += 4) {
            float4 b4[8];
#pragma unroll
            for (int j = 0; j < 8; ++j) b4[j] = *(float4*)&Bs[tx + 16 * j][k0];
#pragma unroll
            for (int i = 0; i < 8; ++i) {
                float4 a4 = *(float4*)&As[ty + 16 * i][k0];
#pragma unroll
                for (int j = 0; j < 8; ++j) {
                    acc[i][j] += a4.x * b4[j].x + a4.y * b4[j].y +
                                 a4.z * b4[j].z + a4.w * b4[j].w;
                }
            }
        }
        __syncthreads();
    }

    const float* np_ = norms + (size_t)p * 512;
    float na[8], nb[8];
#pragma unroll
    for (int i = 0; i < 8; ++i) na[i] = np_[ti * 128 + ty + 16 * i];
#pragma unroll
    for (int j = 0; j < 8; ++j) nb[j] = np_[tj * 128 + tx + 16 * j];

    const float bwv = bw[p];
    float c0 = -1.f / bwv;
    float c1 = c0 * 0.5f, c2 = c1 * 0.5f, c3 = c2 * 0.5f, c4v = c3 * 0.5f;
    float tot = 0.f;
#pragma unroll
    for (int i = 0; i < 8; ++i) {
#pragma unroll
        for (int j = 0; j < 8; ++j) {
            float d2 = na[i] + nb[j] - 2.f * acc[i][j];
            float kv = __expf(c0 * d2) + __expf(c1 * d2) + __expf(c2 * d2) +
                       __expf(c3 * d2) + __expf(c4v * d2);
            tot += kv;
        }
    }
    tot *= coef;

    for (int off = 32; off > 0; off >>= 1) tot += __shfl_down(tot, off);
    if ((tid & 63) == 0) rbuf[tid >> 6] = tot;
    __syncthreads();
    if (tid == 0) atomicAdd(&mmdv[p], rbuf[0] + rbuf[1] + rbuf[2] + rbuf[3]);
}

// ---------------- K10: loss = sum(wts * mmd) / 65536 ----------------
__global__ void final_loss(const float* __restrict__ wts,
                           const float* __restrict__ mmdv,
                           float* __restrict__ out)
{
    const int t = threadIdx.x;  // 256
    float v = wts[t] * mmdv[t];
    __shared__ float red[256];
    red[t] = v;
    __syncthreads();
    for (int st = 128; st > 0; st >>= 1) {
        if (t < st) red[t] += red[t + st];
        __syncthreads();
    }
    if (t == 0) out[0] = red[0] * (1.f / 65536.f);
}

// ---------------- launch ----------------
extern "C" void kernel_launch(void* const* d_in, const int* in_sizes, int n_in,
                              void* d_out, int out_size, void* d_ws, size_t ws_size,
                              hipStream_t stream)
{
    (void)in_sizes; (void)n_in; (void)out_size; (void)ws_size;
    const float* x    = (const float*)d_in[0];
    const float* wih0 = (const float*)d_in[1];
    const float* whh0 = (const float*)d_in[2];
    const float* bih0 = (const float*)d_in[3];
    const float* bhh0 = (const float*)d_in[4];
    const float* wih1 = (const float*)d_in[5];
    const float* whh1 = (const float*)d_in[6];
    const float* bih1 = (const float*)d_in[7];
    const float* bhh1 = (const float*)d_in[8];
    const float* gw0  = (const float*)d_in[9];
    const float* bg0  = (const float*)d_in[11];
    const float* bb0  = (const float*)d_in[12];
    const float* gw1  = (const float*)d_in[13];
    const float* bg1  = (const float*)d_in[15];
    const float* bb1  = (const float*)d_in[16];
    const float* fcw  = (const float*)d_in[17];
    const float* fcb  = (const float*)d_in[18];

    float* out = (float*)d_out;
    char*  ws  = (char*)d_ws;
    float* xw   = (float*)(ws + XW_OFF);
    float* o1   = (float*)(ws + O1_OFF);
    float* o2   = (float*)(ws + O2_OFF);
    float* y0   = (float*)(ws + Y0_OFF);
    float* y1   = (float*)(ws + Y1_OFF);
    float* mmdv = (float*)(ws + MMD_OFF);
    float* wts  = (float*)(ws + WTS_OFF);
    float* bwv  = (float*)(ws + BW_OFF);
    float* nrm  = (float*)(ws + NRM_OFF);   // aliases xw; valid after 2nd gru_scan

    hipMemsetAsync(y0, 0, (256 * 128 * 2 + 256) * sizeof(float), stream);

    gemm64<<<dim3(1024, 6), 256, 0, stream>>>(x, wih0, bih0, xw, 65536, 384, 128);
    gru_scan<<<256, 768, 0, stream>>>(xw, whh0, bhh0, o1);
    gemm64<<<dim3(1024, 6), 256, 0, stream>>>(o1, wih1, bih1, xw, 65536, 384, 128);
    gru_scan<<<256, 768, 0, stream>>>(xw, whh1, bhh1, o2);

    gate_gemm<<<dim3(4, 2, 32), 256, 0, stream>>>(o1, gw0, y0);
    gate_gemm<<<dim3(4, 2, 32), 256, 0, stream>>>(o2, gw1, y1);
    gate_reduce<<<1, 128, 0, stream>>>(y0, bg0, bb0, wts, out + 3073);
    gate_reduce<<<1, 128, 0, stream>>>(y1, bg1, bb1, wts + 128, out + 3073 + 128);

    fc_kern<<<12, 256, 0, stream>>>(o2, fcw, fcb, out);

    row_norms<<<dim3(128, 2), 512, 0, stream>>>(o1, o2, nrm);   // xw dead from here
    pair_stats<<<256, 256, 0, stream>>>(o1, o2, bwv);
    mmd_kern<<<2560, 256, 0, stream>>>(o1, o2, nrm, bwv, mmdv);
    final_loss<<<1, 256, 0, stream>>>(wts, mmdv, out + 3072);
}

// Round 9
// 937.472 us; speedup vs baseline: 1.1972x; 1.0827x over previous
//
#include <hip/hip_runtime.h>
#include <math.h>

typedef __attribute__((ext_vector_type(8))) short bf16x8;   // 8 bf16 (4 VGPRs)
typedef __attribute__((ext_vector_type(4))) float f32x4;

// ---------------- workspace layout (bytes) ----------------
constexpr size_t XW_OFF  = 0;                                   // 96 MB (dead after 2nd gru)
constexpr size_t O1_OFF  = XW_OFF + 65536ull * 384 * 4;         // 32 MB
constexpr size_t O2_OFF  = O1_OFF + 512ull * 128 * 128 * 4;     // 32 MB
constexpr size_t Y0_OFF  = O2_OFF + 512ull * 128 * 128 * 4;     // 128 KB
constexpr size_t Y1_OFF  = Y0_OFF + 256ull * 128 * 4;           // 128 KB
constexpr size_t MMD_OFF = Y1_OFF + 256ull * 128 * 4;           // 1 KB
constexpr size_t WTS_OFF = MMD_OFF + 256 * 4;                   // 1 KB
constexpr size_t BW_OFF  = WTS_OFF + 256 * 4;                   // 1 KB
// aliases into dead xw region:
constexpr size_t NRM_OFF = XW_OFF;                              // norms[256][512] f32 = 512 KB
constexpr size_t CHI_OFF = XW_OFF + (1ull << 20);               // bf16 hi [256][512][128] = 33.6 MB
constexpr size_t CLO_OFF = CHI_OFF + 36ull * 1024 * 1024;       // bf16 lo, same size

static __device__ __forceinline__ unsigned short f2bf(float x) {
    unsigned u = __float_as_uint(x);
    unsigned r = (u + 0x7FFFu + ((u >> 16) & 1u)) >> 16;
    return (unsigned short)r;
}
static __device__ __forceinline__ float bf2f(unsigned short b) {
    return __uint_as_float((unsigned)b << 16);
}

// ---------------- K1/K3: C[M][N] = A[M][K] @ W[N][K]^T + bias[N] ----------------
__global__ __launch_bounds__(256) void gemm64(const float* __restrict__ A,
                                              const float* __restrict__ W,
                                              const float* __restrict__ bias,
                                              float* __restrict__ C,
                                              int M, int N, int K)
{
    __shared__ __align__(16) float As[64][36];
    __shared__ __align__(16) float Ws[64][36];
    const int tid = threadIdx.x;
    const int tx = tid & 15, ty = tid >> 4;
    const int m0 = blockIdx.x * 64, n0 = blockIdx.y * 64;

    float acc[4][4];
#pragma unroll
    for (int i = 0; i < 4; ++i)
#pragma unroll
        for (int j = 0; j < 4; ++j) acc[i][j] = 0.f;

#pragma unroll 1
    for (int kc = 0; kc < K; kc += 32) {
#pragma unroll
        for (int it = 0; it < 2; ++it) {
            int idx = tid + it * 256;          // 0..511
            int row = idx >> 3;
            int c4  = (idx & 7) * 4;
            float4 va = *(const float4*)(A + (size_t)(m0 + row) * K + kc + c4);
            *(float4*)&As[row][c4] = va;
            float4 vw = *(const float4*)(W + (size_t)(n0 + row) * K + kc + c4);
            *(float4*)&Ws[row][c4] = vw;
        }
        __syncthreads();
#pragma unroll 1
        for (int k0 = 0; k0 < 32; k0 += 4) {
            float4 a4[4], w4[4];
#pragma unroll
            for (int i = 0; i < 4; ++i) a4[i] = *(float4*)&As[ty + 16 * i][k0];
#pragma unroll
            for (int j = 0; j < 4; ++j) w4[j] = *(float4*)&Ws[tx + 16 * j][k0];
#pragma unroll
            for (int i = 0; i < 4; ++i)
#pragma unroll
                for (int j = 0; j < 4; ++j) {
                    acc[i][j] += a4[i].x * w4[j].x + a4[i].y * w4[j].y +
                                 a4[i].z * w4[j].z + a4[i].w * w4[j].w;
                }
        }
        __syncthreads();
    }
#pragma unroll
    for (int i = 0; i < 4; ++i)
#pragma unroll
        for (int j = 0; j < 4; ++j) {
            int r = m0 + ty + 16 * i, c = n0 + tx + 16 * j;
            C[(size_t)r * N + c] = acc[i][j] + bias[c];
        }
}

// ---------------- K2/K4: GRU scan (R8 DPP version, unchanged) ----------------
#define DPPADD(a, ctrl) { int yi_ = __builtin_amdgcn_mov_dpp(__float_as_int(a), ctrl, 0xF, 0xF, true); \
                          a += __int_as_float(yi_); }

__global__ __launch_bounds__(768, 3) void gru_scan(const float* __restrict__ xw,
                                                   const float* __restrict__ whh,
                                                   const float* __restrict__ bhh,
                                                   float* __restrict__ out)
{
    const int b0 = blockIdx.x * 2;
    const int t  = threadIdx.x;            // 0..767
    const int ks = t & 7;
    const int og = t >> 3;                 // 0..95
    const int e  = ks & 3;
    const int rown = ks & 3;
    const int j  = 4 * og + rown;

    const int o0 = 4 * (0 ^ e), o1 = 4 * (1 ^ e), o2 = 4 * (2 ^ e), o3 = 4 * (3 ^ e);

    const float* wb = whh + (size_t)(4 * og) * 128 + 16 * ks;
#define LDQ(r, q, oq) float4 w##r##_##q = *(const float4*)(wb + (r) * 128 + (oq));
    LDQ(0,0,o0) LDQ(0,1,o1) LDQ(0,2,o2) LDQ(0,3,o3)
    LDQ(1,0,o0) LDQ(1,1,o1) LDQ(1,2,o2) LDQ(1,3,o3)
    LDQ(2,0,o0) LDQ(2,1,o1) LDQ(2,2,o2) LDQ(2,3,o3)
    LDQ(3,0,o0) LDQ(3,1,o1) LDQ(3,2,o2) LDQ(3,3,o3)
#undef LDQ
#define PIN(v) asm volatile("" : "+v"(v.x), "+v"(v.y), "+v"(v.z), "+v"(v.w))
    PIN(w0_0); PIN(w0_1); PIN(w0_2); PIN(w0_3);
    PIN(w1_0); PIN(w1_1); PIN(w1_2); PIN(w1_3);
    PIN(w2_0); PIN(w2_1); PIN(w2_2); PIN(w2_3);
    PIN(w3_0); PIN(w3_1); PIN(w3_2); PIN(w3_3);
#undef PIN

    const float bj = bhh[j];

    __shared__ __align__(16) float h_s[2][128];
    __shared__ float rz_s[2][256];
    __shared__ float xn_s[2][128];
    __shared__ float hn_s[2][128];
    if (t < 256) h_s[t >> 7][t & 127] = 0.f;
    __syncthreads();

    const float* xwb0 = xw + (size_t)b0 * 128 * 384;
    const float* xwb1 = xwb0 + 128 * 384;

    float xv0 = 0.f, xv1 = 0.f;
    if (ks < 4) { xv0 = xwb0[j]; xv1 = xwb1[j]; }

#pragma unroll 1
    for (int st = 0; st < 128; ++st) {
        float nx0 = 0.f, nx1 = 0.f;
        if (st < 127 && ks < 4) {
            nx0 = xwb0[(st + 1) * 384 + j];
            nx1 = xwb1[(st + 1) * 384 + j];
        }

#define MQ(q, oq, hp) { float4 hv = *(const float4*)((hp) + (oq));                       \
        a0 += w0_##q.x * hv.x + w0_##q.y * hv.y + w0_##q.z * hv.z + w0_##q.w * hv.w;     \
        a1 += w1_##q.x * hv.x + w1_##q.y * hv.y + w1_##q.z * hv.z + w1_##q.w * hv.w;     \
        a2 += w2_##q.x * hv.x + w2_##q.y * hv.y + w2_##q.z * hv.z + w2_##q.w * hv.w;     \
        a3 += w3_##q.x * hv.x + w3_##q.y * hv.y + w3_##q.z * hv.z + w3_##q.w * hv.w; }

        const float* hp0 = &h_s[0][16 * ks];
        float a0 = 0.f, a1 = 0.f, a2 = 0.f, a3 = 0.f;
        MQ(0, o0, hp0) MQ(1, o1, hp0) MQ(2, o2, hp0) MQ(3, o3, hp0)
        DPPADD(a0, 0xB1) DPPADD(a0, 0x4E)
        DPPADD(a1, 0xB1) DPPADD(a1, 0x4E)
        DPPADD(a2, 0xB1) DPPADD(a2, 0x4E)
        DPPADD(a3, 0xB1) DPPADD(a3, 0x4E)
        float hw0 = ((rown == 0) ? a0 : (rown == 1) ? a1 : (rown == 2) ? a2 : a3);
        hw0 += __shfl_xor(hw0, 4);
        hw0 += bj;

        const float* hp1 = &h_s[1][16 * ks];
        a0 = 0.f; a1 = 0.f; a2 = 0.f; a3 = 0.f;
        MQ(0, o0, hp1) MQ(1, o1, hp1) MQ(2, o2, hp1) MQ(3, o3, hp1)
        DPPADD(a0, 0xB1) DPPADD(a0, 0x4E)
        DPPADD(a1, 0xB1) DPPADD(a1, 0x4E)
        DPPADD(a2, 0xB1) DPPADD(a2, 0x4E)
        DPPADD(a3, 0xB1) DPPADD(a3, 0x4E)
        float hw1 = ((rown == 0) ? a0 : (rown == 1) ? a1 : (rown == 2) ? a2 : a3);
        hw1 += __shfl_xor(hw1, 4);
        hw1 += bj;
#undef MQ

        if (ks < 4) {
            const int g = j >> 7, u = j & 127;
            if (g == 0)      { rz_s[0][u] = xv0 + hw0;        rz_s[1][u] = xv1 + hw1; }
            else if (g == 1) { rz_s[0][128 + u] = xv0 + hw0;  rz_s[1][128 + u] = xv1 + hw1; }
            else             { xn_s[0][u] = xv0; hn_s[0][u] = hw0;
                               xn_s[1][u] = xv1; hn_s[1][u] = hw1; }
        }
        __syncthreads();
        if (t < 256) {
            const int rr = t >> 7, uu = t & 127;
            float r = 1.f / (1.f + __expf(-rz_s[rr][uu]));
            float z = 1.f / (1.f + __expf(-rz_s[rr][128 + uu]));
            float xa = xn_s[rr][uu] + r * hn_s[rr][uu];
            float ex = __expf(-2.f * fabsf(xa));
            float th = (1.f - ex) / (1.f + ex);
            th = copysignf(th, xa);
            float hnew = (1.f - z) * th + z * h_s[rr][uu];
            h_s[rr][uu] = hnew;
            out[((size_t)(b0 + rr) * 128 + st) * 128 + uu] = hnew;
        }
        __syncthreads();
        xv0 = nx0; xv1 = nx1;
    }
}

// ---------------- K5: y[256][128] += xall @ gw^T (split-K, atomic) ----------------
__global__ __launch_bounds__(256) void gate_gemm(const float* __restrict__ o,
                                                 const float* __restrict__ gw,
                                                 float* __restrict__ y)
{
    __shared__ __align__(16) float As[64][36];
    __shared__ __align__(16) float Ws[64][36];
    const int tid = threadIdx.x;
    const int tx = tid & 15, ty = tid >> 4;
    const int m0 = blockIdx.x * 64, n0 = blockIdx.y * 64;
    const int k0beg = blockIdx.z * 1024;

    float acc[4][4];
#pragma unroll
    for (int i = 0; i < 4; ++i)
#pragma unroll
        for (int j = 0; j < 4; ++j) acc[i][j] = 0.f;

#pragma unroll 1
    for (int kc = k0beg; kc < k0beg + 1024; kc += 32) {
#pragma unroll
        for (int it = 0; it < 2; ++it) {
            int idx = tid + it * 256;
            int row = idx >> 3;
            int c4  = (idx & 7) * 4;
            int kap = kc + c4;
            int s = kap >> 8, half = (kap >> 7) & 1, h = kap & 127;
            float4 va = *(const float4*)(o + ((size_t)(m0 + row + 256 * half) * 128 + s) * 128 + h);
            *(float4*)&As[row][c4] = va;
            float4 vw = *(const float4*)(gw + (size_t)(n0 + row) * 32768 + kap);
            *(float4*)&Ws[row][c4] = vw;
        }
        __syncthreads();
#pragma unroll 1
        for (int k0 = 0; k0 < 32; k0 += 4) {
            float4 a4[4], w4[4];
#pragma unroll
            for (int i = 0; i < 4; ++i) a4[i] = *(float4*)&As[ty + 16 * i][k0];
#pragma unroll
            for (int j = 0; j < 4; ++j) w4[j] = *(float4*)&Ws[tx + 16 * j][k0];
#pragma unroll
            for (int i = 0; i < 4; ++i)
#pragma unroll
                for (int j = 0; j < 4; ++j) {
                    acc[i][j] += a4[i].x * w4[j].x + a4[i].y * w4[j].y +
                                 a4[i].z * w4[j].z + a4[i].w * w4[j].w;
                }
        }
        __syncthreads();
    }
#pragma unroll
    for (int i = 0; i < 4; ++i)
#pragma unroll
        for (int j = 0; j < 4; ++j) {
            int r = m0 + ty + 16 * i, c = n0 + tx + 16 * j;
            atomicAdd(&y[r * 128 + c], acc[i][j]);
        }
}

// ---------------- K6: BN + sigmoid-mean + softmax -> weights (128) ----------------
__global__ void gate_reduce(const float* __restrict__ y,
                            const float* __restrict__ gamma,
                            const float* __restrict__ beta,
                            float* __restrict__ wts_ws,
                            float* __restrict__ wts_out)
{
    const int o = threadIdx.x;   // 128 threads
    float sum = 0.f, sumsq = 0.f;
    for (int b = 0; b < 256; ++b) {
        float v = y[b * 128 + o];
        sum += v; sumsq += v * v;
    }
    float m = sum * (1.f / 256.f);
    float var = sumsq * (1.f / 256.f) - m * m;
    float inv = rsqrtf(var + 1e-5f);
    float g = gamma[o], be = beta[o];
    float sw = 0.f;
    for (int b = 0; b < 256; ++b) {
        float v = y[b * 128 + o];
        float t = g * (v - m) * inv + be;
        sw += 1.f / (1.f + __expf(-t));
    }
    float wo = sw * (1.f / 256.f);

    __shared__ float red[128];
    red[o] = wo;
    __syncthreads();
    for (int st = 64; st > 0; st >>= 1) {
        if (o < st) red[o] = fmaxf(red[o], red[o + st]);
        __syncthreads();
    }
    float mx = red[0];
    __syncthreads();
    float e = __expf(wo - mx);
    red[o] = e;
    __syncthreads();
    for (int st = 64; st > 0; st >>= 1) {
        if (o < st) red[o] += red[o + st];
        __syncthreads();
    }
    float r = e / red[0];
    wts_ws[o] = r;
    wts_out[o] = r;
}

// ---------------- K7: fc_out = o2[:, -1, :] @ fc_w^T + fc_b ----------------
__global__ void fc_kern(const float* __restrict__ o2,
                        const float* __restrict__ fw,
                        const float* __restrict__ fb,
                        float* __restrict__ out)
{
    int gid = blockIdx.x * blockDim.x + threadIdx.x;
    if (gid >= 3072) return;
    int b = gid / 6, oo = gid - b * 6;
    const float* xr = o2 + ((size_t)b * 128 + 127) * 128;
    const float* wr = fw + oo * 128;
    float acc = fb[oo];
#pragma unroll 16
    for (int k = 0; k < 128; ++k) acc += xr[k] * wr[k];
    out[gid] = acc;
}

// ---------------- K8a: per-row norms (f32, exact) ----------------
__global__ __launch_bounds__(512) void row_norms(const float* __restrict__ o1,
                                                 const float* __restrict__ o2,
                                                 float* __restrict__ norms)
{
    const int s = blockIdx.x;          // 128
    const int l = blockIdx.y;          // 2
    const float* o = l ? o2 : o1;
    const int i = threadIdx.x;         // 512 rows
    const float* r = o + ((size_t)i * 128 + s) * 128;
    float acc = 0.f;
#pragma unroll
    for (int k = 0; k < 128; k += 4) {
        float4 v = *(const float4*)(r + k);
        acc += v.x * v.x + v.y * v.y + v.z * v.z + v.w * v.w;
    }
    norms[((size_t)l * 128 + s) * 512 + i] = acc;
}

// ---------------- K8b: bf16 hi/lo conversion, pair-major layout ----------------
// chi/clo[((l*128+s)*512 + i)*128 + h]
__global__ __launch_bounds__(512) void cvt_bf16(const float* __restrict__ o1,
                                                const float* __restrict__ o2,
                                                unsigned short* __restrict__ chi,
                                                unsigned short* __restrict__ clo)
{
    const int s = blockIdx.x;          // 128
    const int l = blockIdx.y;          // 2
    const float* o = l ? o2 : o1;
    const int t = threadIdx.x;         // 512
    const int h4 = (t & 31) * 4;
    const size_t pb = ((size_t)l * 128 + s) * 512 * 128;
#pragma unroll 1
    for (int i = t >> 5; i < 512; i += 16) {
        float4 v = *(const float4*)(o + ((size_t)i * 128 + s) * 128 + h4);
        ushort4 uh, ul;
        uh.x = f2bf(v.x); ul.x = f2bf(v.x - bf2f(uh.x));
        uh.y = f2bf(v.y); ul.y = f2bf(v.y - bf2f(uh.y));
        uh.z = f2bf(v.z); ul.z = f2bf(v.z - bf2f(uh.z));
        uh.w = f2bf(v.w); ul.w = f2bf(v.w - bf2f(uh.w));
        *(ushort4*)(chi + pb + (size_t)i * 128 + h4) = uh;
        *(ushort4*)(clo + pb + (size_t)i * 128 + h4) = ul;
    }
}

// ---------------- K8c: per-pair bandwidth ----------------
__global__ void pair_stats(const float* __restrict__ o1,
                           const float* __restrict__ o2,
                           float* __restrict__ bw)
{
    const int p = blockIdx.x;          // 256 pairs
    const int l = p >> 7, s = p & 127;
    const float* o = l ? o2 : o1;
    const int tid = threadIdx.x;       // 256
    const int h = tid & 127, half = tid >> 7;

    float acc_u = 0.f, acc_sq = 0.f;
    for (int r = 0; r < 256; ++r) {
        int i = half * 256 + r;
        float v = o[((size_t)i * 128 + s) * 128 + h];
        acc_u += v; acc_sq += v * v;
    }
    __shared__ float u2[256];
    __shared__ float red[256];
    u2[tid] = acc_u;
    red[tid] = acc_sq;
    __syncthreads();
    for (int st = 128; st > 0; st >>= 1) {
        if (tid < st) red[tid] += red[tid + st];
        __syncthreads();
    }
    float S1 = red[0];
    __syncthreads();
    float uu = 0.f;
    if (tid < 128) { float t = u2[tid] + u2[tid + 128]; uu = t * t; }
    red[tid] = uu;
    __syncthreads();
    for (int st = 128; st > 0; st >>= 1) {
        if (tid < st) red[tid] += red[tid + st];
        __syncthreads();
    }
    if (tid == 0) {
        float S2 = red[0];
        float d2s = 1024.f * S1 - 2.f * S2;
        bw[p] = d2s / (512.f * 512.f - 512.f) * 0.25f;
    }
}

// ---------------- K9: MMD via bf16 hi/lo MFMA Gram, no LDS staging ----------------
// 4 waves (2x2) per block, each wave owns a 64x64 sub-tile = 4x4 frags of 16x16.
// A/B frag loads directly from global (L2-resident, pair-major layout):
// lane supplies T[row = base + (lane&15)][k = kc + 8*(lane>>4) + e], a 16B load.
// acc = hi*hi + hi*lo + lo*hi (3 MFMAs) -> ~2^-17 relative Gram error.
// C/D layout (m89-verified): col = lane&15, row = (lane>>4)*4 + reg.
__global__ __launch_bounds__(256) void mmd_kern(const unsigned short* __restrict__ chi,
                                                const unsigned short* __restrict__ clo,
                                                const float* __restrict__ norms,
                                                const float* __restrict__ bw,
                                                float* __restrict__ mmdv)
{
    const int lin = blockIdx.x;               // 0..2559
    const int v   = (lin & 7) * 320 + (lin >> 3);
    const int p   = v / 10;                   // pair
    const int tp  = v - p * 10;               // tile-pair
    int ti, tj;
    if (tp < 4)      { ti = 0; tj = tp; }
    else if (tp < 7) { ti = 1; tj = tp - 3; }
    else if (tp < 9) { ti = 2; tj = tp - 5; }
    else             { ti = 3; tj = 3; }
    const float sgn  = ((ti < 2) == (tj < 2)) ? 1.f : -1.f;
    const float coef = sgn * ((ti == tj) ? 1.f : 2.f);

    const int tid  = threadIdx.x;
    const int lane = tid & 63;
    const int wave = tid >> 6;                // 0..3
    const int wm = wave >> 1, wn = wave & 1;
    const int r16 = lane & 15;
    const int kq  = lane >> 4;                // 0..3

    const size_t pbase = (size_t)p * 512 * 128;
    const int arow = ti * 128 + wm * 64 + r16;
    const int brow = tj * 128 + wn * 64 + r16;

    f32x4 acc[4][4];
#pragma unroll
    for (int mf = 0; mf < 4; ++mf)
#pragma unroll
        for (int nf = 0; nf < 4; ++nf) acc[mf][nf] = (f32x4){0.f, 0.f, 0.f, 0.f};

#pragma unroll 1
    for (int kc = 0; kc < 128; kc += 32) {
        const size_t koff = (size_t)kc + 8 * kq;
        bf16x8 ah[4], al[4], bh[4], bl[4];
#pragma unroll
        for (int mf = 0; mf < 4; ++mf) {
            size_t off = pbase + (size_t)(arow + mf * 16) * 128 + koff;
            ah[mf] = *(const bf16x8*)(chi + off);
            al[mf] = *(const bf16x8*)(clo + off);
        }
#pragma unroll
        for (int nf = 0; nf < 4; ++nf) {
            size_t off = pbase + (size_t)(brow + nf * 16) * 128 + koff;
            bh[nf] = *(const bf16x8*)(chi + off);
            bl[nf] = *(const bf16x8*)(clo + off);
        }
#pragma unroll
        for (int mf = 0; mf < 4; ++mf)
#pragma unroll
            for (int nf = 0; nf < 4; ++nf) {
                acc[mf][nf] = __builtin_amdgcn_mfma_f32_16x16x32_bf16(ah[mf], bh[nf], acc[mf][nf], 0, 0, 0);
                acc[mf][nf] = __builtin_amdgcn_mfma_f32_16x16x32_bf16(ah[mf], bl[nf], acc[mf][nf], 0, 0, 0);
                acc[mf][nf] = __builtin_amdgcn_mfma_f32_16x16x32_bf16(al[mf], bh[nf], acc[mf][nf], 0, 0, 0);
            }
    }

    // epilogue: d2 -> 5-kernel sum via one exp + squarings (c_i = c0 / 2^i)
    const float* np_ = norms + (size_t)p * 512;
    float na[4][4], nb[4];
#pragma unroll
    for (int mf = 0; mf < 4; ++mf)
#pragma unroll
        for (int r = 0; r < 4; ++r)
            na[mf][r] = np_[ti * 128 + wm * 64 + mf * 16 + (lane >> 4) * 4 + r];
#pragma unroll
    for (int nf = 0; nf < 4; ++nf)
        nb[nf] = np_[tj * 128 + wn * 64 + nf * 16 + (lane & 15)];

    const float bwv = bw[p];
    const float c4 = -1.f / (bwv * 16.f);
    float tot = 0.f;
#pragma unroll
    for (int mf = 0; mf < 4; ++mf)
#pragma unroll
        for (int nf = 0; nf < 4; ++nf)
#pragma unroll
            for (int r = 0; r < 4; ++r) {
                float d2 = na[mf][r] + nb[nf] - 2.f * acc[mf][nf][r];
                float e4 = __expf(c4 * d2);
                float e3 = e4 * e4;
                float e2 = e3 * e3;
                float e1 = e2 * e2;
                float e0 = e1 * e1;
                tot += ((e0 + e1) + (e2 + e3)) + e4;
            }
    tot *= coef;

    __shared__ float rbuf[4];
    for (int off = 32; off > 0; off >>= 1) tot += __shfl_down(tot, off);
    if ((tid & 63) == 0) rbuf[tid >> 6] = tot;
    __syncthreads();
    if (tid == 0) atomicAdd(&mmdv[p], rbuf[0] + rbuf[1] + rbuf[2] + rbuf[3]);
}

// ---------------- K10: loss = sum(wts * mmd) / 65536 ----------------
__global__ void final_loss(const float* __restrict__ wts,
                           const float* __restrict__ mmdv,
                           float* __restrict__ out)
{
    const int t = threadIdx.x;  // 256
    float v = wts[t] * mmdv[t];
    __shared__ float red[256];
    red[t] = v;
    __syncthreads();
    for (int st = 128; st > 0; st >>= 1) {
        if (t < st) red[t] += red[t + st];
        __syncthreads();
    }
    if (t == 0) out[0] = red[0] * (1.f / 65536.f);
}

// ---------------- launch ----------------
extern "C" void kernel_launch(void* const* d_in, const int* in_sizes, int n_in,
                              void* d_out, int out_size, void* d_ws, size_t ws_size,
                              hipStream_t stream)
{
    (void)in_sizes; (void)n_in; (void)out_size; (void)ws_size;
    const float* x    = (const float*)d_in[0];
    const float* wih0 = (const float*)d_in[1];
    const float* whh0 = (const float*)d_in[2];
    const float* bih0 = (const float*)d_in[3];
    const float* bhh0 = (const float*)d_in[4];
    const float* wih1 = (const float*)d_in[5];
    const float* whh1 = (const float*)d_in[6];
    const float* bih1 = (const float*)d_in[7];
    const float* bhh1 = (const float*)d_in[8];
    const float* gw0  = (const float*)d_in[9];
    const float* bg0  = (const float*)d_in[11];
    const float* bb0  = (const float*)d_in[12];
    const float* gw1  = (const float*)d_in[13];
    const float* bg1  = (const float*)d_in[15];
    const float* bb1  = (const float*)d_in[16];
    const float* fcw  = (const float*)d_in[17];
    const float* fcb  = (const float*)d_in[18];

    float* out = (float*)d_out;
    char*  ws  = (char*)d_ws;
    float* xw   = (float*)(ws + XW_OFF);
    float* o1   = (float*)(ws + O1_OFF);
    float* o2   = (float*)(ws + O2_OFF);
    float* y0   = (float*)(ws + Y0_OFF);
    float* y1   = (float*)(ws + Y1_OFF);
    float* mmdv = (float*)(ws + MMD_OFF);
    float* wts  = (float*)(ws + WTS_OFF);
    float* bwv  = (float*)(ws + BW_OFF);
    float* nrm  = (float*)(ws + NRM_OFF);            // aliases xw; valid after 2nd gru
    unsigned short* chi = (unsigned short*)(ws + CHI_OFF);
    unsigned short* clo = (unsigned short*)(ws + CLO_OFF);

    hipMemsetAsync(y0, 0, (256 * 128 * 2 + 256) * sizeof(float), stream);

    gemm64<<<dim3(1024, 6), 256, 0, stream>>>(x, wih0, bih0, xw, 65536, 384, 128);
    gru_scan<<<256, 768, 0, stream>>>(xw, whh0, bhh0, o1);
    gemm64<<<dim3(1024, 6), 256, 0, stream>>>(o1, wih1, bih1, xw, 65536, 384, 128);
    gru_scan<<<256, 768, 0, stream>>>(xw, whh1, bhh1, o2);

    gate_gemm<<<dim3(4, 2, 32), 256, 0, stream>>>(o1, gw0, y0);
    gate_gemm<<<dim3(4, 2, 32), 256, 0, stream>>>(o2, gw1, y1);
    gate_reduce<<<1, 128, 0, stream>>>(y0, bg0, bb0, wts, out + 3073);
    gate_reduce<<<1, 128, 0, stream>>>(y1, bg1, bb1, wts + 128, out + 3073 + 128);

    fc_kern<<<12, 256, 0, stream>>>(o2, fcw, fcb, out);

    row_norms<<<dim3(128, 2), 512, 0, stream>>>(o1, o2, nrm);      // xw dead from here
    cvt_bf16<<<dim3(128, 2), 512, 0, stream>>>(o1, o2, chi, clo);
    pair_stats<<<256, 256, 0, stream>>>(o1, o2, bwv);
    mmd_kern<<<2560, 256, 0, stream>>>(chi, clo, nrm, bwv, mmdv);
    final_loss<<<1, 256, 0, stream>>>(wts, mmdv, out + 3072);
}

// Round 10
// 927.685 us; speedup vs baseline: 1.2099x; 1.0105x over previous
//
#include <hip/hip_runtime.h>
#include <math.h>

typedef __attribute__((ext_vector_type(8))) short bf16x8;   // 8 bf16 (4 VGPRs)
typedef __attribute__((ext_vector_type(4))) float f32x4;

// ---------------- workspace layout (bytes) ----------------
constexpr size_t XW_OFF  = 0;                                   // 96 MB (dead after 2nd gru)
constexpr size_t O1_OFF  = XW_OFF + 65536ull * 384 * 4;         // 32 MB
constexpr size_t O2_OFF  = O1_OFF + 512ull * 128 * 128 * 4;     // 32 MB
constexpr size_t Y0_OFF  = O2_OFF + 512ull * 128 * 128 * 4;     // 128 KB
constexpr size_t Y1_OFF  = Y0_OFF + 256ull * 128 * 4;           // 128 KB
constexpr size_t MMD_OFF = Y1_OFF + 256ull * 128 * 4;           // 1 KB
constexpr size_t WTS_OFF = MMD_OFF + 256 * 4;                   // 1 KB
constexpr size_t BW_OFF  = WTS_OFF + 256 * 4;                   // 1 KB
// aliases into dead xw region:
constexpr size_t NRM_OFF = XW_OFF;                              // norms[256][512] f32 = 512 KB
constexpr size_t CHI_OFF = XW_OFF + (1ull << 20);               // bf16 hi [256][512][128] = 33.6 MB
constexpr size_t CLO_OFF = CHI_OFF + 36ull * 1024 * 1024;       // bf16 lo, same size

static __device__ __forceinline__ unsigned short f2bf(float x) {
    unsigned u = __float_as_uint(x);
    unsigned r = (u + 0x7FFFu + ((u >> 16) & 1u)) >> 16;
    return (unsigned short)r;
}
static __device__ __forceinline__ float bf2f(unsigned short b) {
    return __uint_as_float((unsigned)b << 16);
}

// ---------------- K1/K3: C[M][N] = A[M][K] @ W[N][K]^T + bias[N] ----------------
__global__ __launch_bounds__(256) void gemm64(const float* __restrict__ A,
                                              const float* __restrict__ W,
                                              const float* __restrict__ bias,
                                              float* __restrict__ C,
                                              int M, int N, int K)
{
    __shared__ __align__(16) float As[64][36];
    __shared__ __align__(16) float Ws[64][36];
    const int tid = threadIdx.x;
    const int tx = tid & 15, ty = tid >> 4;
    const int m0 = blockIdx.x * 64, n0 = blockIdx.y * 64;

    float acc[4][4];
#pragma unroll
    for (int i = 0; i < 4; ++i)
#pragma unroll
        for (int j = 0; j < 4; ++j) acc[i][j] = 0.f;

#pragma unroll 1
    for (int kc = 0; kc < K; kc += 32) {
#pragma unroll
        for (int it = 0; it < 2; ++it) {
            int idx = tid + it * 256;          // 0..511
            int row = idx >> 3;
            int c4  = (idx & 7) * 4;
            float4 va = *(const float4*)(A + (size_t)(m0 + row) * K + kc + c4);
            *(float4*)&As[row][c4] = va;
            float4 vw = *(const float4*)(W + (size_t)(n0 + row) * K + kc + c4);
            *(float4*)&Ws[row][c4] = vw;
        }
        __syncthreads();
#pragma unroll 1
        for (int k0 = 0; k0 < 32; k0 += 4) {
            float4 a4[4], w4[4];
#pragma unroll
            for (int i = 0; i < 4; ++i) a4[i] = *(float4*)&As[ty + 16 * i][k0];
#pragma unroll
            for (int j = 0; j < 4; ++j) w4[j] = *(float4*)&Ws[tx + 16 * j][k0];
#pragma unroll
            for (int i = 0; i < 4; ++i)
#pragma unroll
                for (int j = 0; j < 4; ++j) {
                    acc[i][j] += a4[i].x * w4[j].x + a4[i].y * w4[j].y +
                                 a4[i].z * w4[j].z + a4[i].w * w4[j].w;
                }
        }
        __syncthreads();
    }
#pragma unroll
    for (int i = 0; i < 4; ++i)
#pragma unroll
        for (int j = 0; j < 4; ++j) {
            int r = m0 + ty + 16 * i, c = n0 + tx + 16 * j;
            C[(size_t)r * N + c] = acc[i][j] + bias[c];
        }
}

// ---------------- K2/K4: GRU scan ----------------
// R9 post-mortem: VGPR=56 < 64 weight floats -> compiler STILL refetched whh
// from L2 every step (6.4 GB L2 reads = the whole 193us). Root cause: plain
// loads are rematerializable; asm "+v" pins the VALUE but not the LOAD.
// Fix: issue the 16 weight loads via asm volatile global_load_dwordx4 with
// "=v" outputs + inline s_waitcnt (prologue-only). Non-rematerializable ->
// values must stay register-resident for all 128 steps.
#define DPPADD(a, ctrl) { int yi_ = __builtin_amdgcn_mov_dpp(__float_as_int(a), ctrl, 0xF, 0xF, true); \
                          a += __int_as_float(yi_); }

__global__ __launch_bounds__(768, 3) void gru_scan(const float* __restrict__ xw,
                                                   const float* __restrict__ whh,
                                                   const float* __restrict__ bhh,
                                                   float* __restrict__ out)
{
    const int b0 = blockIdx.x * 2;
    const int t  = threadIdx.x;            // 0..767
    const int ks = t & 7;
    const int og = t >> 3;                 // 0..95
    const int e  = ks & 3;
    const int rown = ks & 3;
    const int j  = 4 * og + rown;

    const int o0 = 4 * (0 ^ e), o1 = 4 * (1 ^ e), o2 = 4 * (2 ^ e), o3 = 4 * (3 ^ e);

    const float* wb = whh + (size_t)(4 * og) * 128 + 16 * ks;
    // asm loads: non-rematerializable -> forced register residency
#define LDQ(r, q, oq) float4 w##r##_##q;                                              \
    { const float4* ap_ = (const float4*)(wb + (r) * 128 + (oq));                     \
      asm volatile("global_load_dwordx4 %0, %1, off\n\ts_waitcnt vmcnt(0)"            \
                   : "=v"(w##r##_##q) : "v"(ap_)); }
    LDQ(0,0,o0) LDQ(0,1,o1) LDQ(0,2,o2) LDQ(0,3,o3)
    LDQ(1,0,o0) LDQ(1,1,o1) LDQ(1,2,o2) LDQ(1,3,o3)
    LDQ(2,0,o0) LDQ(2,1,o1) LDQ(2,2,o2) LDQ(2,3,o3)
    LDQ(3,0,o0) LDQ(3,1,o1) LDQ(3,2,o2) LDQ(3,3,o3)
#undef LDQ

    const float bj = bhh[j];

    __shared__ __align__(16) float h_s[2][128];
    __shared__ float rz_s[2][256];
    __shared__ float xn_s[2][128];
    __shared__ float hn_s[2][128];
    if (t < 256) h_s[t >> 7][t & 127] = 0.f;
    __syncthreads();

    const float* xwb0 = xw + (size_t)b0 * 128 * 384;
    const float* xwb1 = xwb0 + 128 * 384;

    float xv0 = 0.f, xv1 = 0.f;
    if (ks < 4) { xv0 = xwb0[j]; xv1 = xwb1[j]; }

#pragma unroll 1
    for (int st = 0; st < 128; ++st) {
        float nx0 = 0.f, nx1 = 0.f;
        if (st < 127 && ks < 4) {
            nx0 = xwb0[(st + 1) * 384 + j];
            nx1 = xwb1[(st + 1) * 384 + j];
        }

#define MQ(q, oq, hp) { float4 hv = *(const float4*)((hp) + (oq));                       \
        a0 += w0_##q.x * hv.x + w0_##q.y * hv.y + w0_##q.z * hv.z + w0_##q.w * hv.w;     \
        a1 += w1_##q.x * hv.x + w1_##q.y * hv.y + w1_##q.z * hv.z + w1_##q.w * hv.w;     \
        a2 += w2_##q.x * hv.x + w2_##q.y * hv.y + w2_##q.z * hv.z + w2_##q.w * hv.w;     \
        a3 += w3_##q.x * hv.x + w3_##q.y * hv.y + w3_##q.z * hv.z + w3_##q.w * hv.w; }

        const float* hp0 = &h_s[0][16 * ks];
        float a0 = 0.f, a1 = 0.f, a2 = 0.f, a3 = 0.f;
        MQ(0, o0, hp0) MQ(1, o1, hp0) MQ(2, o2, hp0) MQ(3, o3, hp0)
        DPPADD(a0, 0xB1) DPPADD(a0, 0x4E)
        DPPADD(a1, 0xB1) DPPADD(a1, 0x4E)
        DPPADD(a2, 0xB1) DPPADD(a2, 0x4E)
        DPPADD(a3, 0xB1) DPPADD(a3, 0x4E)
        float hw0 = ((rown == 0) ? a0 : (rown == 1) ? a1 : (rown == 2) ? a2 : a3);
        hw0 += __shfl_xor(hw0, 4);
        hw0 += bj;

        const float* hp1 = &h_s[1][16 * ks];
        a0 = 0.f; a1 = 0.f; a2 = 0.f; a3 = 0.f;
        MQ(0, o0, hp1) MQ(1, o1, hp1) MQ(2, o2, hp1) MQ(3, o3, hp1)
        DPPADD(a0, 0xB1) DPPADD(a0, 0x4E)
        DPPADD(a1, 0xB1) DPPADD(a1, 0x4E)
        DPPADD(a2, 0xB1) DPPADD(a2, 0x4E)
        DPPADD(a3, 0xB1) DPPADD(a3, 0x4E)
        float hw1 = ((rown == 0) ? a0 : (rown == 1) ? a1 : (rown == 2) ? a2 : a3);
        hw1 += __shfl_xor(hw1, 4);
        hw1 += bj;
#undef MQ

        if (ks < 4) {
            const int g = j >> 7, u = j & 127;
            if (g == 0)      { rz_s[0][u] = xv0 + hw0;        rz_s[1][u] = xv1 + hw1; }
            else if (g == 1) { rz_s[0][128 + u] = xv0 + hw0;  rz_s[1][128 + u] = xv1 + hw1; }
            else             { xn_s[0][u] = xv0; hn_s[0][u] = hw0;
                               xn_s[1][u] = xv1; hn_s[1][u] = hw1; }
        }
        __syncthreads();
        if (t < 256) {
            const int rr = t >> 7, uu = t & 127;
            float r = 1.f / (1.f + __expf(-rz_s[rr][uu]));
            float z = 1.f / (1.f + __expf(-rz_s[rr][128 + uu]));
            float xa = xn_s[rr][uu] + r * hn_s[rr][uu];
            float ex = __expf(-2.f * fabsf(xa));
            float th = (1.f - ex) / (1.f + ex);
            th = copysignf(th, xa);
            float hnew = (1.f - z) * th + z * h_s[rr][uu];
            h_s[rr][uu] = hnew;
            out[((size_t)(b0 + rr) * 128 + st) * 128 + uu] = hnew;
        }
        __syncthreads();
        xv0 = nx0; xv1 = nx1;
    }
}

// ---------------- K5: y[256][128] += xall @ gw^T (split-K, atomic) ----------------
__global__ __launch_bounds__(256) void gate_gemm(const float* __restrict__ o,
                                                 const float* __restrict__ gw,
                                                 float* __restrict__ y)
{
    __shared__ __align__(16) float As[64][36];
    __shared__ __align__(16) float Ws[64][36];
    const int tid = threadIdx.x;
    const int tx = tid & 15, ty = tid >> 4;
    const int m0 = blockIdx.x * 64, n0 = blockIdx.y * 64;
    const int k0beg = blockIdx.z * 1024;

    float acc[4][4];
#pragma unroll
    for (int i = 0; i < 4; ++i)
#pragma unroll
        for (int j = 0; j < 4; ++j) acc[i][j] = 0.f;

#pragma unroll 1
    for (int kc = k0beg; kc < k0beg + 1024; kc += 32) {
#pragma unroll
        for (int it = 0; it < 2; ++it) {
            int idx = tid + it * 256;
            int row = idx >> 3;
            int c4  = (idx & 7) * 4;
            int kap = kc + c4;
            int s = kap >> 8, half = (kap >> 7) & 1, h = kap & 127;
            float4 va = *(const float4*)(o + ((size_t)(m0 + row + 256 * half) * 128 + s) * 128 + h);
            *(float4*)&As[row][c4] = va;
            float4 vw = *(const float4*)(gw + (size_t)(n0 + row) * 32768 + kap);
            *(float4*)&Ws[row][c4] = vw;
        }
        __syncthreads();
#pragma unroll 1
        for (int k0 = 0; k0 < 32; k0 += 4) {
            float4 a4[4], w4[4];
#pragma unroll
            for (int i = 0; i < 4; ++i) a4[i] = *(float4*)&As[ty + 16 * i][k0];
#pragma unroll
            for (int j = 0; j < 4; ++j) w4[j] = *(float4*)&Ws[tx + 16 * j][k0];
#pragma unroll
            for (int i = 0; i < 4; ++i)
#pragma unroll
                for (int j = 0; j < 4; ++j) {
                    acc[i][j] += a4[i].x * w4[j].x + a4[i].y * w4[j].y +
                                 a4[i].z * w4[j].z + a4[i].w * w4[j].w;
                }
        }
        __syncthreads();
    }
#pragma unroll
    for (int i = 0; i < 4; ++i)
#pragma unroll
        for (int j = 0; j < 4; ++j) {
            int r = m0 + ty + 16 * i, c = n0 + tx + 16 * j;
            atomicAdd(&y[r * 128 + c], acc[i][j]);
        }
}

// ---------------- K6: BN + sigmoid-mean + softmax -> weights (128) ----------------
__global__ void gate_reduce(const float* __restrict__ y,
                            const float* __restrict__ gamma,
                            const float* __restrict__ beta,
                            float* __restrict__ wts_ws,
                            float* __restrict__ wts_out)
{
    const int o = threadIdx.x;   // 128 threads
    float sum = 0.f, sumsq = 0.f;
    for (int b = 0; b < 256; ++b) {
        float v = y[b * 128 + o];
        sum += v; sumsq += v * v;
    }
    float m = sum * (1.f / 256.f);
    float var = sumsq * (1.f / 256.f) - m * m;
    float inv = rsqrtf(var + 1e-5f);
    float g = gamma[o], be = beta[o];
    float sw = 0.f;
    for (int b = 0; b < 256; ++b) {
        float v = y[b * 128 + o];
        float t = g * (v - m) * inv + be;
        sw += 1.f / (1.f + __expf(-t));
    }
    float wo = sw * (1.f / 256.f);

    __shared__ float red[128];
    red[o] = wo;
    __syncthreads();
    for (int st = 64; st > 0; st >>= 1) {
        if (o < st) red[o] = fmaxf(red[o], red[o + st]);
        __syncthreads();
    }
    float mx = red[0];
    __syncthreads();
    float e = __expf(wo - mx);
    red[o] = e;
    __syncthreads();
    for (int st = 64; st > 0; st >>= 1) {
        if (o < st) red[o] += red[o + st];
        __syncthreads();
    }
    float r = e / red[0];
    wts_ws[o] = r;
    wts_out[o] = r;
}

// ---------------- K7: fc_out = o2[:, -1, :] @ fc_w^T + fc_b ----------------
__global__ void fc_kern(const float* __restrict__ o2,
                        const float* __restrict__ fw,
                        const float* __restrict__ fb,
                        float* __restrict__ out)
{
    int gid = blockIdx.x * blockDim.x + threadIdx.x;
    if (gid >= 3072) return;
    int b = gid / 6, oo = gid - b * 6;
    const float* xr = o2 + ((size_t)b * 128 + 127) * 128;
    const float* wr = fw + oo * 128;
    float acc = fb[oo];
#pragma unroll 16
    for (int k = 0; k < 128; ++k) acc += xr[k] * wr[k];
    out[gid] = acc;
}

// ---------------- K8a: per-row norms (f32, exact) ----------------
__global__ __launch_bounds__(512) void row_norms(const float* __restrict__ o1,
                                                 const float* __restrict__ o2,
                                                 float* __restrict__ norms)
{
    const int s = blockIdx.x;          // 128
    const int l = blockIdx.y;          // 2
    const float* o = l ? o2 : o1;
    const int i = threadIdx.x;         // 512 rows
    const float* r = o + ((size_t)i * 128 + s) * 128;
    float acc = 0.f;
#pragma unroll
    for (int k = 0; k < 128; k += 4) {
        float4 v = *(const float4*)(r + k);
        acc += v.x * v.x + v.y * v.y + v.z * v.z + v.w * v.w;
    }
    norms[((size_t)l * 128 + s) * 512 + i] = acc;
}

// ---------------- K8b: bf16 hi/lo conversion, pair-major layout ----------------
__global__ __launch_bounds__(512) void cvt_bf16(const float* __restrict__ o1,
                                                const float* __restrict__ o2,
                                                unsigned short* __restrict__ chi,
                                                unsigned short* __restrict__ clo)
{
    const int s = blockIdx.x;          // 128
    const int l = blockIdx.y;          // 2
    const float* o = l ? o2 : o1;
    const int t = threadIdx.x;         // 512
    const int h4 = (t & 31) * 4;
    const size_t pb = ((size_t)l * 128 + s) * 512 * 128;
#pragma unroll 1
    for (int i = t >> 5; i < 512; i += 16) {
        float4 v = *(const float4*)(o + ((size_t)i * 128 + s) * 128 + h4);
        ushort4 uh, ul;
        uh.x = f2bf(v.x); ul.x = f2bf(v.x - bf2f(uh.x));
        uh.y = f2bf(v.y); ul.y = f2bf(v.y - bf2f(uh.y));
        uh.z = f2bf(v.z); ul.z = f2bf(v.z - bf2f(uh.z));
        uh.w = f2bf(v.w); ul.w = f2bf(v.w - bf2f(uh.w));
        *(ushort4*)(chi + pb + (size_t)i * 128 + h4) = uh;
        *(ushort4*)(clo + pb + (size_t)i * 128 + h4) = ul;
    }
}

// ---------------- K8c: per-pair bandwidth ----------------
__global__ void pair_stats(const float* __restrict__ o1,
                           const float* __restrict__ o2,
                           float* __restrict__ bw)
{
    const int p = blockIdx.x;          // 256 pairs
    const int l = p >> 7, s = p & 127;
    const float* o = l ? o2 : o1;
    const int tid = threadIdx.x;       // 256
    const int h = tid & 127, half = tid >> 7;

    float acc_u = 0.f, acc_sq = 0.f;
    for (int r = 0; r < 256; ++r) {
        int i = half * 256 + r;
        float v = o[((size_t)i * 128 + s) * 128 + h];
        acc_u += v; acc_sq += v * v;
    }
    __shared__ float u2[256];
    __shared__ float red[256];
    u2[tid] = acc_u;
    red[tid] = acc_sq;
    __syncthreads();
    for (int st = 128; st > 0; st >>= 1) {
        if (tid < st) red[tid] += red[tid + st];
        __syncthreads();
    }
    float S1 = red[0];
    __syncthreads();
    float uu = 0.f;
    if (tid < 128) { float t = u2[tid] + u2[tid + 128]; uu = t * t; }
    red[tid] = uu;
    __syncthreads();
    for (int st = 128; st > 0; st >>= 1) {
        if (tid < st) red[tid] += red[tid + st];
        __syncthreads();
    }
    if (tid == 0) {
        float S2 = red[0];
        float d2s = 1024.f * S1 - 2.f * S2;
        bw[p] = d2s / (512.f * 512.f - 512.f) * 0.25f;
    }
}

// ---------------- K9: MMD via bf16 hi/lo MFMA Gram, no LDS staging ----------------
__global__ __launch_bounds__(256) void mmd_kern(const unsigned short* __restrict__ chi,
                                                const unsigned short* __restrict__ clo,
                                                const float* __restrict__ norms,
                                                const float* __restrict__ bw,
                                                float* __restrict__ mmdv)
{
    const int lin = blockIdx.x;               // 0..2559
    const int v   = (lin & 7) * 320 + (lin >> 3);
    const int p   = v / 10;                   // pair
    const int tp  = v - p * 10;               // tile-pair
    int ti, tj;
    if (tp < 4)      { ti = 0; tj = tp; }
    else if (tp < 7) { ti = 1; tj = tp - 3; }
    else if (tp < 9) { ti = 2; tj = tp - 5; }
    else             { ti = 3; tj = 3; }
    const float sgn  = ((ti < 2) == (tj < 2)) ? 1.f : -1.f;
    const float coef = sgn * ((ti == tj) ? 1.f : 2.f);

    const int tid  = threadIdx.x;
    const int lane = tid & 63;
    const int wave = tid >> 6;                // 0..3
    const int wm = wave >> 1, wn = wave & 1;
    const int r16 = lane & 15;
    const int kq  = lane >> 4;                // 0..3

    const size_t pbase = (size_t)p * 512 * 128;
    const int arow = ti * 128 + wm * 64 + r16;
    const int brow = tj * 128 + wn * 64 + r16;

    f32x4 acc[4][4];
#pragma unroll
    for (int mf = 0; mf < 4; ++mf)
#pragma unroll
        for (int nf = 0; nf < 4; ++nf) acc[mf][nf] = (f32x4){0.f, 0.f, 0.f, 0.f};

#pragma unroll 1
    for (int kc = 0; kc < 128; kc += 32) {
        const size_t koff = (size_t)kc + 8 * kq;
        bf16x8 ah[4], al[4], bh[4], bl[4];
#pragma unroll
        for (int mf = 0; mf < 4; ++mf) {
            size_t off = pbase + (size_t)(arow + mf * 16) * 128 + koff;
            ah[mf] = *(const bf16x8*)(chi + off);
            al[mf] = *(const bf16x8*)(clo + off);
        }
#pragma unroll
        for (int nf = 0; nf < 4; ++nf) {
            size_t off = pbase + (size_t)(brow + nf * 16) * 128 + koff;
            bh[nf] = *(const bf16x8*)(chi + off);
            bl[nf] = *(const bf16x8*)(clo + off);
        }
#pragma unroll
        for (int mf = 0; mf < 4; ++mf)
#pragma unroll
            for (int nf = 0; nf < 4; ++nf) {
                acc[mf][nf] = __builtin_amdgcn_mfma_f32_16x16x32_bf16(ah[mf], bh[nf], acc[mf][nf], 0, 0, 0);
                acc[mf][nf] = __builtin_amdgcn_mfma_f32_16x16x32_bf16(ah[mf], bl[nf], acc[mf][nf], 0, 0, 0);
                acc[mf][nf] = __builtin_amdgcn_mfma_f32_16x16x32_bf16(al[mf], bh[nf], acc[mf][nf], 0, 0, 0);
            }
    }

    const float* np_ = norms + (size_t)p * 512;
    float na[4][4], nb[4];
#pragma unroll
    for (int mf = 0; mf < 4; ++mf)
#pragma unroll
        for (int r = 0; r < 4; ++r)
            na[mf][r] = np_[ti * 128 + wm * 64 + mf * 16 + (lane >> 4) * 4 + r];
#pragma unroll
    for (int nf = 0; nf < 4; ++nf)
        nb[nf] = np_[tj * 128 + wn * 64 + nf * 16 + (lane & 15)];

    const float bwv = bw[p];
    const float c4 = -1.f / (bwv * 16.f);
    float tot = 0.f;
#pragma unroll
    for (int mf = 0; mf < 4; ++mf)
#pragma unroll
        for (int nf = 0; nf < 4; ++nf)
#pragma unroll
            for (int r = 0; r < 4; ++r) {
                float d2 = na[mf][r] + nb[nf] - 2.f * acc[mf][nf][r];
                float e4 = __expf(c4 * d2);
                float e3 = e4 * e4;
                float e2 = e3 * e3;
                float e1 = e2 * e2;
                float e0 = e1 * e1;
                tot += ((e0 + e1) + (e2 + e3)) + e4;
            }
    tot *= coef;

    __shared__ float rbuf[4];
    for (int off = 32; off > 0; off >>= 1) tot += __shfl_down(tot, off);
    if ((tid & 63) == 0) rbuf[tid >> 6] = tot;
    __syncthreads();
    if (tid == 0) atomicAdd(&mmdv[p], rbuf[0] + rbuf[1] + rbuf[2] + rbuf[3]);
}

// ---------------- K10: loss = sum(wts * mmd) / 65536 ----------------
__global__ void final_loss(const float* __restrict__ wts,
                           const float* __restrict__ mmdv,
                           float* __restrict__ out)
{
    const int t = threadIdx.x;  // 256
    float v = wts[t] * mmdv[t];
    __shared__ float red[256];
    red[t] = v;
    __syncthreads();
    for (int st = 128; st > 0; st >>= 1) {
        if (t < st) red[t] += red[t + st];
        __syncthreads();
    }
    if (t == 0) out[0] = red[0] * (1.f / 65536.f);
}

// ---------------- launch ----------------
extern "C" void kernel_launch(void* const* d_in, const int* in_sizes, int n_in,
                              void* d_out, int out_size, void* d_ws, size_t ws_size,
                              hipStream_t stream)
{
    (void)in_sizes; (void)n_in; (void)out_size; (void)ws_size;
    const float* x    = (const float*)d_in[0];
    const float* wih0 = (const float*)d_in[1];
    const float* whh0 = (const float*)d_in[2];
    const float* bih0 = (const float*)d_in[3];
    const float* bhh0 = (const float*)d_in[4];
    const float* wih1 = (const float*)d_in[5];
    const float* whh1 = (const float*)d_in[6];
    const float* bih1 = (const float*)d_in[7];
    const float* bhh1 = (const float*)d_in[8];
    const float* gw0  = (const float*)d_in[9];
    const float* bg0  = (const float*)d_in[11];
    const float* bb0  = (const float*)d_in[12];
    const float* gw1  = (const float*)d_in[13];
    const float* bg1  = (const float*)d_in[15];
    const float* bb1  = (const float*)d_in[16];
    const float* fcw  = (const float*)d_in[17];
    const float* fcb  = (const float*)d_in[18];

    float* out = (float*)d_out;
    char*  ws  = (char*)d_ws;
    float* xw   = (float*)(ws + XW_OFF);
    float* o1   = (float*)(ws + O1_OFF);
    float* o2   = (float*)(ws + O2_OFF);
    float* y0   = (float*)(ws + Y0_OFF);
    float* y1   = (float*)(ws + Y1_OFF);
    float* mmdv = (float*)(ws + MMD_OFF);
    float* wts  = (float*)(ws + WTS_OFF);
    float* bwv  = (float*)(ws + BW_OFF);
    float* nrm  = (float*)(ws + NRM_OFF);            // aliases xw; valid after 2nd gru
    unsigned short* chi = (unsigned short*)(ws + CHI_OFF);
    unsigned short* clo = (unsigned short*)(ws + CLO_OFF);

    hipMemsetAsync(y0, 0, (256 * 128 * 2 + 256) * sizeof(float), stream);

    gemm64<<<dim3(1024, 6), 256, 0, stream>>>(x, wih0, bih0, xw, 65536, 384, 128);
    gru_scan<<<256, 768, 0, stream>>>(xw, whh0, bhh0, o1);
    gemm64<<<dim3(1024, 6), 256, 0, stream>>>(o1, wih1, bih1, xw, 65536, 384, 128);
    gru_scan<<<256, 768, 0, stream>>>(xw, whh1, bhh1, o2);

    gate_gemm<<<dim3(4, 2, 32), 256, 0, stream>>>(o1, gw0, y0);
    gate_gemm<<<dim3(4, 2, 32), 256, 0, stream>>>(o2, gw1, y1);
    gate_reduce<<<1, 128, 0, stream>>>(y0, bg0, bb0, wts, out + 3073);
    gate_reduce<<<1, 128, 0, stream>>>(y1, bg1, bb1, wts + 128, out + 3073 + 128);

    fc_kern<<<12, 256, 0, stream>>>(o2, fcw, fcb, out);

    row_norms<<<dim3(128, 2), 512, 0, stream>>>(o1, o2, nrm);      // xw dead from here
    cvt_bf16<<<dim3(128, 2), 512, 0, stream>>>(o1, o2, chi, clo);
    pair_stats<<<256, 256, 0, stream>>>(o1, o2, bwv);
    mmd_kern<<<2560, 256, 0, stream>>>(chi, clo, nrm, bwv, mmdv);
    final_loss<<<1, 256, 0, stream>>>(wts, mmdv, out + 3072);
}

// Round 11
// 818.904 us; speedup vs baseline: 1.3706x; 1.1328x over previous
//
#include <hip/hip_runtime.h>
#include <math.h>

typedef __attribute__((ext_vector_type(8))) short bf16x8;   // 8 bf16 (4 VGPRs)
typedef __attribute__((ext_vector_type(4))) float f32x4;

// ---------------- workspace layout (bytes) ----------------
constexpr size_t XW_OFF  = 0;                                   // 96 MB (gemm out; dead after 2nd gru)
constexpr size_t O1_OFF  = XW_OFF + 65536ull * 384 * 4;         // 32 MB
constexpr size_t O2_OFF  = O1_OFF + 512ull * 128 * 128 * 4;     // 32 MB (also A-bf16 staging pre-gru2)
constexpr size_t Y0_OFF  = O2_OFF + 512ull * 128 * 128 * 4;     // 128 KB
constexpr size_t Y1_OFF  = Y0_OFF + 256ull * 128 * 4;           // 128 KB
constexpr size_t MMD_OFF = Y1_OFF + 256ull * 128 * 4;           // 1 KB
constexpr size_t WTS_OFF = MMD_OFF + 256 * 4;                   // 1 KB
constexpr size_t BW_OFF  = WTS_OFF + 256 * 4;                   // 1 KB
constexpr size_t WBF_OFF = BW_OFF + 4096;                       // wih bf16 hi/lo x2 layers = 384 KB
// aliases into dead regions:
constexpr size_t NRM_OFF = XW_OFF;                              // norms (after gru2)
constexpr size_t CHI_OFF = XW_OFF + (1ull << 20);               // mmd bf16 hi
constexpr size_t CLO_OFF = CHI_OFF + 36ull * 1024 * 1024;       // mmd bf16 lo
constexpr size_t ABH_OFF = O2_OFF;                              // gemm A bf16 hi (16 MB)
constexpr size_t ABL_OFF = O2_OFF + 16ull * 1024 * 1024;        // gemm A bf16 lo (16 MB)

static __device__ __forceinline__ unsigned short f2bf(float x) {
    unsigned u = __float_as_uint(x);
    unsigned r = (u + 0x7FFFu + ((u >> 16) & 1u)) >> 16;
    return (unsigned short)r;
}
static __device__ __forceinline__ float bf2f(unsigned short b) {
    return __uint_as_float((unsigned)b << 16);
}

// ---------------- K0a: W f32 -> bf16 hi/lo (384x128) ----------------
__global__ __launch_bounds__(256) void cvt_w(const float* __restrict__ W,
                                             unsigned short* __restrict__ whi,
                                             unsigned short* __restrict__ wlo)
{
    int f = blockIdx.x * 256 + threadIdx.x;    // float4 index, 12288 total
    if (f >= 12288) return;
    float4 v = ((const float4*)W)[f];
    ushort4 uh, ul;
    uh.x = f2bf(v.x); ul.x = f2bf(v.x - bf2f(uh.x));
    uh.y = f2bf(v.y); ul.y = f2bf(v.y - bf2f(uh.y));
    uh.z = f2bf(v.z); ul.z = f2bf(v.z - bf2f(uh.z));
    uh.w = f2bf(v.w); ul.w = f2bf(v.w - bf2f(uh.w));
    *(ushort4*)(whi + 4 * f) = uh;
    *(ushort4*)(wlo + 4 * f) = ul;
}

// ---------------- K0b: A f32 [M][128] -> bf16 hi/lo (row-major) ----------------
__global__ __launch_bounds__(256) void cvt_a(const float* __restrict__ A,
                                             unsigned short* __restrict__ ahi,
                                             unsigned short* __restrict__ alo)
{
    const int t = threadIdx.x;
#pragma unroll
    for (int it = 0; it < 4; ++it) {
        size_t f = (size_t)blockIdx.x * 1024 + it * 256 + t;   // float4 idx, 2,097,152 total
        float4 v = ((const float4*)A)[f];
        ushort4 uh, ul;
        uh.x = f2bf(v.x); ul.x = f2bf(v.x - bf2f(uh.x));
        uh.y = f2bf(v.y); ul.y = f2bf(v.y - bf2f(uh.y));
        uh.z = f2bf(v.z); ul.z = f2bf(v.z - bf2f(uh.z));
        uh.w = f2bf(v.w); ul.w = f2bf(v.w - bf2f(uh.w));
        *(ushort4*)(ahi + 4 * f) = uh;
        *(ushort4*)(alo + 4 * f) = ul;
    }
}

// ---------------- K1/K3: C[M][384] = A[M][128] @ W[384][128]^T + bias (MFMA) ----------------
// bf16 hi/lo: acc = hi*hi + hi*lo + lo*hi (~2^-17 rel). 128x128 block tile,
// 4 waves 2x2, per wave 4x4 frags of 16x16x32. Direct-from-global fragment
// loads (mmd_kern-proven pattern). C/D layout: col=lane&15, row=(lane>>4)*4+reg.
__global__ __launch_bounds__(256) void gemm_mfma(const unsigned short* __restrict__ ahi,
                                                 const unsigned short* __restrict__ alo,
                                                 const unsigned short* __restrict__ whi,
                                                 const unsigned short* __restrict__ wlo,
                                                 const float* __restrict__ bias,
                                                 float* __restrict__ C)
{
    const int m0 = blockIdx.x * 128;
    const int n0 = blockIdx.y * 128;          // 0,128,256 (N=384)
    const int tid  = threadIdx.x;
    const int lane = tid & 63;
    const int wave = tid >> 6;
    const int wm = wave >> 1, wn = wave & 1;
    const int r16 = lane & 15;
    const int kq  = lane >> 4;

    const int arow = m0 + wm * 64 + r16;
    const int brow = n0 + wn * 64 + r16;

    f32x4 acc[4][4];
#pragma unroll
    for (int mf = 0; mf < 4; ++mf)
#pragma unroll
        for (int nf = 0; nf < 4; ++nf) acc[mf][nf] = (f32x4){0.f, 0.f, 0.f, 0.f};

#pragma unroll 1
    for (int kc = 0; kc < 128; kc += 32) {
        const int koff = kc + 8 * kq;
        bf16x8 ah[4], al[4], bh[4], bl[4];
#pragma unroll
        for (int mf = 0; mf < 4; ++mf) {
            size_t off = (size_t)(arow + mf * 16) * 128 + koff;
            ah[mf] = *(const bf16x8*)(ahi + off);
            al[mf] = *(const bf16x8*)(alo + off);
        }
#pragma unroll
        for (int nf = 0; nf < 4; ++nf) {
            size_t off = (size_t)(brow + nf * 16) * 128 + koff;
            bh[nf] = *(const bf16x8*)(whi + off);
            bl[nf] = *(const bf16x8*)(wlo + off);
        }
#pragma unroll
        for (int mf = 0; mf < 4; ++mf)
#pragma unroll
            for (int nf = 0; nf < 4; ++nf) {
                acc[mf][nf] = __builtin_amdgcn_mfma_f32_16x16x32_bf16(ah[mf], bh[nf], acc[mf][nf], 0, 0, 0);
                acc[mf][nf] = __builtin_amdgcn_mfma_f32_16x16x32_bf16(ah[mf], bl[nf], acc[mf][nf], 0, 0, 0);
                acc[mf][nf] = __builtin_amdgcn_mfma_f32_16x16x32_bf16(al[mf], bh[nf], acc[mf][nf], 0, 0, 0);
            }
    }

    float nb[4];
#pragma unroll
    for (int nf = 0; nf < 4; ++nf) nb[nf] = bias[n0 + wn * 64 + nf * 16 + r16];

#pragma unroll
    for (int mf = 0; mf < 4; ++mf)
#pragma unroll
        for (int nf = 0; nf < 4; ++nf)
#pragma unroll
            for (int r = 0; r < 4; ++r) {
                int row = m0 + wm * 64 + mf * 16 + kq * 4 + r;
                int col = n0 + wn * 64 + nf * 16 + r16;
                C[(size_t)row * 384 + col] = acc[mf][nf][r] + nb[nf];
            }
}

// ---------------- K2/K4: GRU scan (R10 version) ----------------
#define DPPADD(a, ctrl) { int yi_ = __builtin_amdgcn_mov_dpp(__float_as_int(a), ctrl, 0xF, 0xF, true); \
                          a += __int_as_float(yi_); }

__global__ __launch_bounds__(768, 3) void gru_scan(const float* __restrict__ xw,
                                                   const float* __restrict__ whh,
                                                   const float* __restrict__ bhh,
                                                   float* __restrict__ out)
{
    const int b0 = blockIdx.x * 2;
    const int t  = threadIdx.x;            // 0..767
    const int ks = t & 7;
    const int og = t >> 3;                 // 0..95
    const int e  = ks & 3;
    const int rown = ks & 3;
    const int j  = 4 * og + rown;

    const int o0 = 4 * (0 ^ e), o1 = 4 * (1 ^ e), o2 = 4 * (2 ^ e), o3 = 4 * (3 ^ e);

    const float* wb = whh + (size_t)(4 * og) * 128 + 16 * ks;
#define LDQ(r, q, oq) float4 w##r##_##q;                                              \
    { const float4* ap_ = (const float4*)(wb + (r) * 128 + (oq));                     \
      asm volatile("global_load_dwordx4 %0, %1, off\n\ts_waitcnt vmcnt(0)"            \
                   : "=v"(w##r##_##q) : "v"(ap_)); }
    LDQ(0,0,o0) LDQ(0,1,o1) LDQ(0,2,o2) LDQ(0,3,o3)
    LDQ(1,0,o0) LDQ(1,1,o1) LDQ(1,2,o2) LDQ(1,3,o3)
    LDQ(2,0,o0) LDQ(2,1,o1) LDQ(2,2,o2) LDQ(2,3,o3)
    LDQ(3,0,o0) LDQ(3,1,o1) LDQ(3,2,o2) LDQ(3,3,o3)
#undef LDQ

    const float bj = bhh[j];

    __shared__ __align__(16) float h_s[2][128];
    __shared__ float rz_s[2][256];
    __shared__ float xn_s[2][128];
    __shared__ float hn_s[2][128];
    if (t < 256) h_s[t >> 7][t & 127] = 0.f;
    __syncthreads();

    const float* xwb0 = xw + (size_t)b0 * 128 * 384;
    const float* xwb1 = xwb0 + 128 * 384;

    float xv0 = 0.f, xv1 = 0.f;
    if (ks < 4) { xv0 = xwb0[j]; xv1 = xwb1[j]; }

#pragma unroll 1
    for (int st = 0; st < 128; ++st) {
        float nx0 = 0.f, nx1 = 0.f;
        if (st < 127 && ks < 4) {
            nx0 = xwb0[(st + 1) * 384 + j];
            nx1 = xwb1[(st + 1) * 384 + j];
        }

#define MQ(q, oq, hp) { float4 hv = *(const float4*)((hp) + (oq));                       \
        a0 += w0_##q.x * hv.x + w0_##q.y * hv.y + w0_##q.z * hv.z + w0_##q.w * hv.w;     \
        a1 += w1_##q.x * hv.x + w1_##q.y * hv.y + w1_##q.z * hv.z + w1_##q.w * hv.w;     \
        a2 += w2_##q.x * hv.x + w2_##q.y * hv.y + w2_##q.z * hv.z + w2_##q.w * hv.w;     \
        a3 += w3_##q.x * hv.x + w3_##q.y * hv.y + w3_##q.z * hv.z + w3_##q.w * hv.w; }

        const float* hp0 = &h_s[0][16 * ks];
        float a0 = 0.f, a1 = 0.f, a2 = 0.f, a3 = 0.f;
        MQ(0, o0, hp0) MQ(1, o1, hp0) MQ(2, o2, hp0) MQ(3, o3, hp0)
        DPPADD(a0, 0xB1) DPPADD(a0, 0x4E)
        DPPADD(a1, 0xB1) DPPADD(a1, 0x4E)
        DPPADD(a2, 0xB1) DPPADD(a2, 0x4E)
        DPPADD(a3, 0xB1) DPPADD(a3, 0x4E)
        float hw0 = ((rown == 0) ? a0 : (rown == 1) ? a1 : (rown == 2) ? a2 : a3);
        hw0 += __shfl_xor(hw0, 4);
        hw0 += bj;

        const float* hp1 = &h_s[1][16 * ks];
        a0 = 0.f; a1 = 0.f; a2 = 0.f; a3 = 0.f;
        MQ(0, o0, hp1) MQ(1, o1, hp1) MQ(2, o2, hp1) MQ(3, o3, hp1)
        DPPADD(a0, 0xB1) DPPADD(a0, 0x4E)
        DPPADD(a1, 0xB1) DPPADD(a1, 0x4E)
        DPPADD(a2, 0xB1) DPPADD(a2, 0x4E)
        DPPADD(a3, 0xB1) DPPADD(a3, 0x4E)
        float hw1 = ((rown == 0) ? a0 : (rown == 1) ? a1 : (rown == 2) ? a2 : a3);
        hw1 += __shfl_xor(hw1, 4);
        hw1 += bj;
#undef MQ

        if (ks < 4) {
            const int g = j >> 7, u = j & 127;
            if (g == 0)      { rz_s[0][u] = xv0 + hw0;        rz_s[1][u] = xv1 + hw1; }
            else if (g == 1) { rz_s[0][128 + u] = xv0 + hw0;  rz_s[1][128 + u] = xv1 + hw1; }
            else             { xn_s[0][u] = xv0; hn_s[0][u] = hw0;
                               xn_s[1][u] = xv1; hn_s[1][u] = hw1; }
        }
        __syncthreads();
        if (t < 256) {
            const int rr = t >> 7, uu = t & 127;
            float r = 1.f / (1.f + __expf(-rz_s[rr][uu]));
            float z = 1.f / (1.f + __expf(-rz_s[rr][128 + uu]));
            float xa = xn_s[rr][uu] + r * hn_s[rr][uu];
            float ex = __expf(-2.f * fabsf(xa));
            float th = (1.f - ex) / (1.f + ex);
            th = copysignf(th, xa);
            float hnew = (1.f - z) * th + z * h_s[rr][uu];
            h_s[rr][uu] = hnew;
            out[((size_t)(b0 + rr) * 128 + st) * 128 + uu] = hnew;
        }
        __syncthreads();
        xv0 = nx0; xv1 = nx1;
    }
}

// ---------------- K5: y[256][128] += xall @ gw^T (split-K, atomic) ----------------
__global__ __launch_bounds__(256) void gate_gemm(const float* __restrict__ o,
                                                 const float* __restrict__ gw,
                                                 float* __restrict__ y)
{
    __shared__ __align__(16) float As[64][36];
    __shared__ __align__(16) float Ws[64][36];
    const int tid = threadIdx.x;
    const int tx = tid & 15, ty = tid >> 4;
    const int m0 = blockIdx.x * 64, n0 = blockIdx.y * 64;
    const int k0beg = blockIdx.z * 1024;

    float acc[4][4];
#pragma unroll
    for (int i = 0; i < 4; ++i)
#pragma unroll
        for (int j = 0; j < 4; ++j) acc[i][j] = 0.f;

#pragma unroll 1
    for (int kc = k0beg; kc < k0beg + 1024; kc += 32) {
#pragma unroll
        for (int it = 0; it < 2; ++it) {
            int idx = tid + it * 256;
            int row = idx >> 3;
            int c4  = (idx & 7) * 4;
            int kap = kc + c4;
            int s = kap >> 8, half = (kap >> 7) & 1, h = kap & 127;
            float4 va = *(const float4*)(o + ((size_t)(m0 + row + 256 * half) * 128 + s) * 128 + h);
            *(float4*)&As[row][c4] = va;
            float4 vw = *(const float4*)(gw + (size_t)(n0 + row) * 32768 + kap);
            *(float4*)&Ws[row][c4] = vw;
        }
        __syncthreads();
#pragma unroll 1
        for (int k0 = 0; k0 < 32; k0 += 4) {
            float4 a4[4], w4[4];
#pragma unroll
            for (int i = 0; i < 4; ++i) a4[i] = *(float4*)&As[ty + 16 * i][k0];
#pragma unroll
            for (int j = 0; j < 4; ++j) w4[j] = *(float4*)&Ws[tx + 16 * j][k0];
#pragma unroll
            for (int i = 0; i < 4; ++i)
#pragma unroll
                for (int j = 0; j < 4; ++j) {
                    acc[i][j] += a4[i].x * w4[j].x + a4[i].y * w4[j].y +
                                 a4[i].z * w4[j].z + a4[i].w * w4[j].w;
                }
        }
        __syncthreads();
    }
#pragma unroll
    for (int i = 0; i < 4; ++i)
#pragma unroll
        for (int j = 0; j < 4; ++j) {
            int r = m0 + ty + 16 * i, c = n0 + tx + 16 * j;
            atomicAdd(&y[r * 128 + c], acc[i][j]);
        }
}

// ---------------- K6: BN + sigmoid-mean + softmax -> weights (128) ----------------
__global__ void gate_reduce(const float* __restrict__ y,
                            const float* __restrict__ gamma,
                            const float* __restrict__ beta,
                            float* __restrict__ wts_ws,
                            float* __restrict__ wts_out)
{
    const int o = threadIdx.x;   // 128 threads
    float sum = 0.f, sumsq = 0.f;
    for (int b = 0; b < 256; ++b) {
        float v = y[b * 128 + o];
        sum += v; sumsq += v * v;
    }
    float m = sum * (1.f / 256.f);
    float var = sumsq * (1.f / 256.f) - m * m;
    float inv = rsqrtf(var + 1e-5f);
    float g = gamma[o], be = beta[o];
    float sw = 0.f;
    for (int b = 0; b < 256; ++b) {
        float v = y[b * 128 + o];
        float t = g * (v - m) * inv + be;
        sw += 1.f / (1.f + __expf(-t));
    }
    float wo = sw * (1.f / 256.f);

    __shared__ float red[128];
    red[o] = wo;
    __syncthreads();
    for (int st = 64; st > 0; st >>= 1) {
        if (o < st) red[o] = fmaxf(red[o], red[o + st]);
        __syncthreads();
    }
    float mx = red[0];
    __syncthreads();
    float e = __expf(wo - mx);
    red[o] = e;
    __syncthreads();
    for (int st = 64; st > 0; st >>= 1) {
        if (o < st) red[o] += red[o + st];
        __syncthreads();
    }
    float r = e / red[0];
    wts_ws[o] = r;
    wts_out[o] = r;
}

// ---------------- K7: fc_out = o2[:, -1, :] @ fc_w^T + fc_b ----------------
__global__ void fc_kern(const float* __restrict__ o2,
                        const float* __restrict__ fw,
                        const float* __restrict__ fb,
                        float* __restrict__ out)
{
    int gid = blockIdx.x * blockDim.x + threadIdx.x;
    if (gid >= 3072) return;
    int b = gid / 6, oo = gid - b * 6;
    const float* xr = o2 + ((size_t)b * 128 + 127) * 128;
    const float* wr = fw + oo * 128;
    float acc = fb[oo];
#pragma unroll 16
    for (int k = 0; k < 128; ++k) acc += xr[k] * wr[k];
    out[gid] = acc;
}

// ---------------- K8a: per-row norms (f32, exact) ----------------
__global__ __launch_bounds__(512) void row_norms(const float* __restrict__ o1,
                                                 const float* __restrict__ o2,
                                                 float* __restrict__ norms)
{
    const int s = blockIdx.x;          // 128
    const int l = blockIdx.y;          // 2
    const float* o = l ? o2 : o1;
    const int i = threadIdx.x;         // 512 rows
    const float* r = o + ((size_t)i * 128 + s) * 128;
    float acc = 0.f;
#pragma unroll
    for (int k = 0; k < 128; k += 4) {
        float4 v = *(const float4*)(r + k);
        acc += v.x * v.x + v.y * v.y + v.z * v.z + v.w * v.w;
    }
    norms[((size_t)l * 128 + s) * 512 + i] = acc;
}

// ---------------- K8b: bf16 hi/lo conversion, pair-major layout (for mmd) ----------------
__global__ __launch_bounds__(512) void cvt_bf16(const float* __restrict__ o1,
                                                const float* __restrict__ o2,
                                                unsigned short* __restrict__ chi,
                                                unsigned short* __restrict__ clo)
{
    const int s = blockIdx.x;          // 128
    const int l = blockIdx.y;          // 2
    const float* o = l ? o2 : o1;
    const int t = threadIdx.x;         // 512
    const int h4 = (t & 31) * 4;
    const size_t pb = ((size_t)l * 128 + s) * 512 * 128;
#pragma unroll 1
    for (int i = t >> 5; i < 512; i += 16) {
        float4 v = *(const float4*)(o + ((size_t)i * 128 + s) * 128 + h4);
        ushort4 uh, ul;
        uh.x = f2bf(v.x); ul.x = f2bf(v.x - bf2f(uh.x));
        uh.y = f2bf(v.y); ul.y = f2bf(v.y - bf2f(uh.y));
        uh.z = f2bf(v.z); ul.z = f2bf(v.z - bf2f(uh.z));
        uh.w = f2bf(v.w); ul.w = f2bf(v.w - bf2f(uh.w));
        *(ushort4*)(chi + pb + (size_t)i * 128 + h4) = uh;
        *(ushort4*)(clo + pb + (size_t)i * 128 + h4) = ul;
    }
}

// ---------------- K8c: per-pair bandwidth ----------------
__global__ void pair_stats(const float* __restrict__ o1,
                           const float* __restrict__ o2,
                           float* __restrict__ bw)
{
    const int p = blockIdx.x;          // 256 pairs
    const int l = p >> 7, s = p & 127;
    const float* o = l ? o2 : o1;
    const int tid = threadIdx.x;       // 256
    const int h = tid & 127, half = tid >> 7;

    float acc_u = 0.f, acc_sq = 0.f;
    for (int r = 0; r < 256; ++r) {
        int i = half * 256 + r;
        float v = o[((size_t)i * 128 + s) * 128 + h];
        acc_u += v; acc_sq += v * v;
    }
    __shared__ float u2[256];
    __shared__ float red[256];
    u2[tid] = acc_u;
    red[tid] = acc_sq;
    __syncthreads();
    for (int st = 128; st > 0; st >>= 1) {
        if (tid < st) red[tid] += red[tid + st];
        __syncthreads();
    }
    float S1 = red[0];
    __syncthreads();
    float uu = 0.f;
    if (tid < 128) { float t = u2[tid] + u2[tid + 128]; uu = t * t; }
    red[tid] = uu;
    __syncthreads();
    for (int st = 128; st > 0; st >>= 1) {
        if (tid < st) red[tid] += red[tid + st];
        __syncthreads();
    }
    if (tid == 0) {
        float S2 = red[0];
        float d2s = 1024.f * S1 - 2.f * S2;
        bw[p] = d2s / (512.f * 512.f - 512.f) * 0.25f;
    }
}

// ---------------- K9: MMD via bf16 hi/lo MFMA Gram ----------------
__global__ __launch_bounds__(256) void mmd_kern(const unsigned short* __restrict__ chi,
                                                const unsigned short* __restrict__ clo,
                                                const float* __restrict__ norms,
                                                const float* __restrict__ bw,
                                                float* __restrict__ mmdv)
{
    const int lin = blockIdx.x;               // 0..2559
    const int v   = (lin & 7) * 320 + (lin >> 3);
    const int p   = v / 10;                   // pair
    const int tp  = v - p * 10;               // tile-pair
    int ti, tj;
    if (tp < 4)      { ti = 0; tj = tp; }
    else if (tp < 7) { ti = 1; tj = tp - 3; }
    else if (tp < 9) { ti = 2; tj = tp - 5; }
    else             { ti = 3; tj = 3; }
    const float sgn  = ((ti < 2) == (tj < 2)) ? 1.f : -1.f;
    const float coef = sgn * ((ti == tj) ? 1.f : 2.f);

    const int tid  = threadIdx.x;
    const int lane = tid & 63;
    const int wave = tid >> 6;                // 0..3
    const int wm = wave >> 1, wn = wave & 1;
    const int r16 = lane & 15;
    const int kq  = lane >> 4;                // 0..3

    const size_t pbase = (size_t)p * 512 * 128;
    const int arow = ti * 128 + wm * 64 + r16;
    const int brow = tj * 128 + wn * 64 + r16;

    f32x4 acc[4][4];
#pragma unroll
    for (int mf = 0; mf < 4; ++mf)
#pragma unroll
        for (int nf = 0; nf < 4; ++nf) acc[mf][nf] = (f32x4){0.f, 0.f, 0.f, 0.f};

#pragma unroll 1
    for (int kc = 0; kc < 128; kc += 32) {
        const size_t koff = (size_t)kc + 8 * kq;
        bf16x8 ah[4], al[4], bh[4], bl[4];
#pragma unroll
        for (int mf = 0; mf < 4; ++mf) {
            size_t off = pbase + (size_t)(arow + mf * 16) * 128 + koff;
            ah[mf] = *(const bf16x8*)(chi + off);
            al[mf] = *(const bf16x8*)(clo + off);
        }
#pragma unroll
        for (int nf = 0; nf < 4; ++nf) {
            size_t off = pbase + (size_t)(brow + nf * 16) * 128 + koff;
            bh[nf] = *(const bf16x8*)(chi + off);
            bl[nf] = *(const bf16x8*)(clo + off);
        }
#pragma unroll
        for (int mf = 0; mf < 4; ++mf)
#pragma unroll
            for (int nf = 0; nf < 4; ++nf) {
                acc[mf][nf] = __builtin_amdgcn_mfma_f32_16x16x32_bf16(ah[mf], bh[nf], acc[mf][nf], 0, 0, 0);
                acc[mf][nf] = __builtin_amdgcn_mfma_f32_16x16x32_bf16(ah[mf], bl[nf], acc[mf][nf], 0, 0, 0);
                acc[mf][nf] = __builtin_amdgcn_mfma_f32_16x16x32_bf16(al[mf], bh[nf], acc[mf][nf], 0, 0, 0);
            }
    }

    const float* np_ = norms + (size_t)p * 512;
    float na[4][4], nb[4];
#pragma unroll
    for (int mf = 0; mf < 4; ++mf)
#pragma unroll
        for (int r = 0; r < 4; ++r)
            na[mf][r] = np_[ti * 128 + wm * 64 + mf * 16 + (lane >> 4) * 4 + r];
#pragma unroll
    for (int nf = 0; nf < 4; ++nf)
        nb[nf] = np_[tj * 128 + wn * 64 + nf * 16 + (lane & 15)];

    const float bwv = bw[p];
    const float c4 = -1.f / (bwv * 16.f);
    float tot = 0.f;
#pragma unroll
    for (int mf = 0; mf < 4; ++mf)
#pragma unroll
        for (int nf = 0; nf < 4; ++nf)
#pragma unroll
            for (int r = 0; r < 4; ++r) {
                float d2 = na[mf][r] + nb[nf] - 2.f * acc[mf][nf][r];
                float e4 = __expf(c4 * d2);
                float e3 = e4 * e4;
                float e2 = e3 * e3;
                float e1 = e2 * e2;
                float e0 = e1 * e1;
                tot += ((e0 + e1) + (e2 + e3)) + e4;
            }
    tot *= coef;

    __shared__ float rbuf[4];
    for (int off = 32; off > 0; off >>= 1) tot += __shfl_down(tot, off);
    if ((tid & 63) == 0) rbuf[tid >> 6] = tot;
    __syncthreads();
    if (tid == 0) atomicAdd(&mmdv[p], rbuf[0] + rbuf[1] + rbuf[2] + rbuf[3]);
}

// ---------------- K10: loss = sum(wts * mmd) / 65536 ----------------
__global__ void final_loss(const float* __restrict__ wts,
                           const float* __restrict__ mmdv,
                           float* __restrict__ out)
{
    const int t = threadIdx.x;  // 256
    float v = wts[t] * mmdv[t];
    __shared__ float red[256];
    red[t] = v;
    __syncthreads();
    for (int st = 128; st > 0; st >>= 1) {
        if (t < st) red[t] += red[t + st];
        __syncthreads();
    }
    if (t == 0) out[0] = red[0] * (1.f / 65536.f);
}

// ---------------- launch ----------------
extern "C" void kernel_launch(void* const* d_in, const int* in_sizes, int n_in,
                              void* d_out, int out_size, void* d_ws, size_t ws_size,
                              hipStream_t stream)
{
    (void)in_sizes; (void)n_in; (void)out_size; (void)ws_size;
    const float* x    = (const float*)d_in[0];
    const float* wih0 = (const float*)d_in[1];
    const float* whh0 = (const float*)d_in[2];
    const float* bih0 = (const float*)d_in[3];
    const float* bhh0 = (const float*)d_in[4];
    const float* wih1 = (const float*)d_in[5];
    const float* whh1 = (const float*)d_in[6];
    const float* bih1 = (const float*)d_in[7];
    const float* bhh1 = (const float*)d_in[8];
    const float* gw0  = (const float*)d_in[9];
    const float* bg0  = (const float*)d_in[11];
    const float* bb0  = (const float*)d_in[12];
    const float* gw1  = (const float*)d_in[13];
    const float* bg1  = (const float*)d_in[15];
    const float* bb1  = (const float*)d_in[16];
    const float* fcw  = (const float*)d_in[17];
    const float* fcb  = (const float*)d_in[18];

    float* out = (float*)d_out;
    char*  ws  = (char*)d_ws;
    float* xw   = (float*)(ws + XW_OFF);
    float* o1   = (float*)(ws + O1_OFF);
    float* o2   = (float*)(ws + O2_OFF);
    float* y0   = (float*)(ws + Y0_OFF);
    float* y1   = (float*)(ws + Y1_OFF);
    float* mmdv = (float*)(ws + MMD_OFF);
    float* wts  = (float*)(ws + WTS_OFF);
    float* bwv  = (float*)(ws + BW_OFF);
    float* nrm  = (float*)(ws + NRM_OFF);
    unsigned short* chi  = (unsigned short*)(ws + CHI_OFF);
    unsigned short* clo  = (unsigned short*)(ws + CLO_OFF);
    unsigned short* abh  = (unsigned short*)(ws + ABH_OFF);   // aliases o2 (pre-gru2)
    unsigned short* abl  = (unsigned short*)(ws + ABL_OFF);
    unsigned short* whi0 = (unsigned short*)(ws + WBF_OFF);
    unsigned short* wlo0 = whi0 + 49152;
    unsigned short* whi1 = wlo0 + 49152;
    unsigned short* wlo1 = whi1 + 49152;

    hipMemsetAsync(y0, 0, (256 * 128 * 2 + 256) * sizeof(float), stream);

    cvt_w<<<48, 256, 0, stream>>>(wih0, whi0, wlo0);
    cvt_w<<<48, 256, 0, stream>>>(wih1, whi1, wlo1);

    cvt_a<<<2048, 256, 0, stream>>>(x, abh, abl);
    gemm_mfma<<<dim3(512, 3), 256, 0, stream>>>(abh, abl, whi0, wlo0, bih0, xw);
    gru_scan<<<256, 768, 0, stream>>>(xw, whh0, bhh0, o1);

    cvt_a<<<2048, 256, 0, stream>>>(o1, abh, abl);
    gemm_mfma<<<dim3(512, 3), 256, 0, stream>>>(abh, abl, whi1, wlo1, bih1, xw);
    gru_scan<<<256, 768, 0, stream>>>(xw, whh1, bhh1, o2);   // overwrites abh/abl (safe: gemm L2 done)

    gate_gemm<<<dim3(4, 2, 32), 256, 0, stream>>>(o1, gw0, y0);
    gate_gemm<<<dim3(4, 2, 32), 256, 0, stream>>>(o2, gw1, y1);
    gate_reduce<<<1, 128, 0, stream>>>(y0, bg0, bb0, wts, out + 3073);
    gate_reduce<<<1, 128, 0, stream>>>(y1, bg1, bb1, wts + 128, out + 3073 + 128);

    fc_kern<<<12, 256, 0, stream>>>(o2, fcw, fcb, out);

    row_norms<<<dim3(128, 2), 512, 0, stream>>>(o1, o2, nrm);      // xw dead from here
    cvt_bf16<<<dim3(128, 2), 512, 0, stream>>>(o1, o2, chi, clo);
    pair_stats<<<256, 256, 0, stream>>>(o1, o2, bwv);
    mmd_kern<<<2560, 256, 0, stream>>>(chi, clo, nrm, bwv, mmdv);
    final_loss<<<1, 256, 0, stream>>>(wts, mmdv, out + 3072);
}